// Round 4
// baseline (1126.401 us; speedup 1.0000x reference)
//
#include <hip/hip_runtime.h>

typedef unsigned short u16;   // raw bf16 bits (INTERNAL storage only)

constexpr int Nn  = 50000;
constexpr int Ee  = 500000;
constexpr int ET  = Nn + Ee;      // edges incl. self-loops
constexpr int FIN = 128;
constexpr int FE  = 16;
constexpr int Hh  = 8;
constexpr int C1  = 32, HC1 = 256;
constexpr int C2  = 16, HC2 = 128;
constexpr float NS  = 0.2f;
constexpr float EPS = 1e-5f;

__device__ __forceinline__ float b2f(u16 u) { return __uint_as_float(((unsigned)u) << 16); }
__device__ __forceinline__ u16 f2b(float f) {
  unsigned u = __float_as_uint(f);
  u += 0x7FFF + ((u >> 16) & 1);          // round-to-nearest-even
  return (u16)(u >> 16);
}

template <int PC>
__device__ __forceinline__ void ldbf(const u16* p, float* o) {
  if constexpr (PC == 4) {
    ushort4 u = *reinterpret_cast<const ushort4*>(p);
    o[0] = b2f(u.x); o[1] = b2f(u.y); o[2] = b2f(u.z); o[3] = b2f(u.w);
  } else {
    ushort2 u = *reinterpret_cast<const ushort2*>(p);
    o[0] = b2f(u.x); o[1] = b2f(u.y);
  }
}
template <int PC>
__device__ __forceinline__ void stbf(u16* p, const float* v) {
  if constexpr (PC == 4) {
    ushort4 u; u.x = f2b(v[0]); u.y = f2b(v[1]); u.z = f2b(v[2]); u.w = f2b(v[3]);
    *reinterpret_cast<ushort4*>(p) = u;
  } else {
    ushort2 u; u.x = f2b(v[0]); u.y = f2b(v[1]);
    *reinterpret_cast<ushort2*>(p) = u;
  }
}

// 4-wide loaders for the GEMM A operand (fp32 input or bf16 internal)
__device__ __forceinline__ void ld4(const float* p, float* o) {
  float4 a = *reinterpret_cast<const float4*>(p);
  o[0] = a.x; o[1] = a.y; o[2] = a.z; o[3] = a.w;
}
__device__ __forceinline__ void ld4(const u16* p, float* o) {
  ushort4 a = *reinterpret_cast<const ushort4*>(p);
  o[0] = b2f(a.x); o[1] = b2f(a.y); o[2] = b2f(a.z); o[3] = b2f(a.w);
}

// ---------------- edge_attr mean (for self-loop fill) ----------------
__global__ void k_ea_mean(const float* __restrict__ ea, float* __restrict__ ea_mean) {
  __shared__ float s[256];
  int f  = threadIdx.x & 15;
  int r0 = (threadIdx.x >> 4) + blockIdx.x * 16;
  float acc = 0.f;
  for (int e = r0; e < Ee; e += gridDim.x * 16) acc += ea[e * FE + f];
  s[threadIdx.x] = acc;
  __syncthreads();
  if (threadIdx.x < 16) {
    float t = 0.f;
    for (int r = 0; r < 16; r++) t += s[r * 16 + threadIdx.x];
    atomicAdd(&ea_mean[threadIdx.x], t * (1.f / Ee));
  }
}

// ---------------- CSR build (by destination) ----------------
__global__ void k_deg(const int* __restrict__ ei, int* __restrict__ deg) {
  int e = blockIdx.x * 256 + threadIdx.x;
  if (e >= ET) return;
  int d = (e < Ee) ? ei[Ee + e] : (e - Ee);
  if ((unsigned)d >= (unsigned)Nn) d = 0;   // safety clamp
  atomicAdd(&deg[d], 1);
}

__global__ __launch_bounds__(1024) void k_scan(const int* __restrict__ deg, int* __restrict__ rowptr) {
  const int T = 1024;
  int t = threadIdx.x;
  const int CH = (Nn + T - 1) / T;  // 49
  int base = t * CH;
  int sum = 0;
  for (int i = 0; i < CH; i++) {
    int idx = base + i;
    if (idx < Nn) sum += deg[idx];
  }
  __shared__ int s[T];
  s[t] = sum;
  __syncthreads();
  for (int off = 1; off < T; off <<= 1) {
    int v = (t >= off) ? s[t - off] : 0;
    __syncthreads();
    s[t] += v;
    __syncthreads();
  }
  int run = (t == 0) ? 0 : s[t - 1];
  for (int i = 0; i < CH; i++) {
    int idx = base + i;
    if (idx < Nn) { rowptr[idx] = run; run += deg[idx]; }
  }
  if (t == T - 1) rowptr[Nn] = run;  // == ET
}

__global__ void k_scatter(const int* __restrict__ ei, const int* __restrict__ rowptr,
                          int* __restrict__ cursor, int* __restrict__ srcp,
                          int* __restrict__ eidp) {
  int e = blockIdx.x * 256 + threadIdx.x;
  if (e >= ET) return;
  int s, d;
  if (e < Ee) { s = ei[e]; d = ei[Ee + e]; } else { s = d = e - Ee; }
  if ((unsigned)s >= (unsigned)Nn) s = 0;   // safety clamp
  if ((unsigned)d >= (unsigned)Nn) d = 0;
  int pos = rowptr[d] + atomicAdd(&cursor[d], 1);
  srcp[pos] = s; eidp[pos] = e;
}

// ------- fp32 tiled GEMM: C[M,NN] = A[M,KK] @ W[KK,NN] + bias; C stored bf16 -------
template <int KK, int NN, typename AT>
__global__ __launch_bounds__(256) void k_gemm(const AT* __restrict__ A, const float* __restrict__ W,
                                              const float* __restrict__ bias, u16* __restrict__ C, int M) {
  __shared__ float As[16][68];
  __shared__ float Bs[16][68];
  int tid = threadIdx.x;
  int tx = tid & 15, ty = tid >> 4;
  int row0 = blockIdx.y * 64;
  int col0 = blockIdx.x * 64;
  float acc[4][4] = {};
  for (int kb = 0; kb < KK; kb += 16) {
    {  // A tile: 64 rows x 16 k, each thread 4 consecutive k
      int v = tid * 4;
      int kk = v & 15, rr = v >> 4;
      int r = row0 + rr;
      float a[4] = {0.f, 0.f, 0.f, 0.f};
      if (r < M) ld4(&A[(long)r * KK + kb + kk], a);
      As[kk + 0][rr] = a[0]; As[kk + 1][rr] = a[1];
      As[kk + 2][rr] = a[2]; As[kk + 3][rr] = a[3];
    }
    {  // W tile: 16 k x 64 cols
      int v = tid * 4;
      int cc = v & 63, kk = v >> 6;
      float4 w = *reinterpret_cast<const float4*>(&W[(long)(kb + kk) * NN + col0 + cc]);
      Bs[kk][cc + 0] = w.x; Bs[kk][cc + 1] = w.y;
      Bs[kk][cc + 2] = w.z; Bs[kk][cc + 3] = w.w;
    }
    __syncthreads();
#pragma unroll
    for (int kk = 0; kk < 16; kk++) {
      float a0 = As[kk][ty * 4 + 0], a1 = As[kk][ty * 4 + 1];
      float a2 = As[kk][ty * 4 + 2], a3 = As[kk][ty * 4 + 3];
      float b0 = Bs[kk][tx * 4 + 0], b1 = Bs[kk][tx * 4 + 1];
      float b2 = Bs[kk][tx * 4 + 2], b3 = Bs[kk][tx * 4 + 3];
      acc[0][0] += a0 * b0; acc[0][1] += a0 * b1; acc[0][2] += a0 * b2; acc[0][3] += a0 * b3;
      acc[1][0] += a1 * b0; acc[1][1] += a1 * b1; acc[1][2] += a1 * b2; acc[1][3] += a1 * b3;
      acc[2][0] += a2 * b0; acc[2][1] += a2 * b1; acc[2][2] += a2 * b2; acc[2][3] += a2 * b3;
      acc[3][0] += a3 * b0; acc[3][1] += a3 * b1; acc[3][2] += a3 * b2; acc[3][3] += a3 * b3;
    }
    __syncthreads();
  }
#pragma unroll
  for (int r = 0; r < 4; r++) {
    int rr = row0 + ty * 4 + r;
    if (rr >= M) continue;
    int cc0 = col0 + tx * 4;
    float v[4];
#pragma unroll
    for (int c = 0; c < 4; c++) v[c] = acc[r][c] + bias[cc0 + c];
    stbf<4>(&C[(long)rr * NN + cc0], v);
  }
}

// ---- fused GATv2 attention: logits + online softmax + aggregation, wave per node ----
// Lane covers PC=HC/64 consecutive channels; lanes 8h..8h+7 cover head h
// (holds for both HC1/C1 and HC2/C2). shfl_xor over {1,2,4} reduces within a head.
template <int HC, int C>
__global__ __launch_bounds__(256) void k_node_attn(
    const int* __restrict__ rowptr, const int* __restrict__ srcp, const int* __restrict__ eidp,
    const u16* __restrict__ xl, const float* __restrict__ We, const float* __restrict__ att,
    const float* __restrict__ edge_attr, const float* __restrict__ ea_mean,
    const float* __restrict__ bo, u16* __restrict__ out) {
  constexpr int PC = HC / 64;
  __shared__ float sWe[FE * HC];
  __shared__ float sAtt[HC];
  for (int t = threadIdx.x; t < FE * HC; t += 256) sWe[t] = We[t];
  for (int t = threadIdx.x; t < HC; t += 256) sAtt[t] = att[t];
  __syncthreads();
  int lane = threadIdx.x & 63;
  int i = (blockIdx.x << 2) + (threadIdx.x >> 6);
  if (i >= Nn) return;
  int c0 = lane * PC;
  float xd[PC];
  ldbf<PC>(&xl[(long)i * HC + c0], xd);
  float m = -1e30f, l = 0.f;
  float acc[PC];
#pragma unroll
  for (int j = 0; j < PC; j++) acc[j] = 0.f;
  int p0 = rowptr[i], p1 = rowptr[i + 1];
  for (int p = p0; p < p1; p++) {
    int s = srcp[p], eid = eidp[p];
    if ((unsigned)s >= (unsigned)Nn) s = 0;       // safety clamp
    float eav[FE];
    if ((unsigned)eid < (unsigned)Ee) {
      const float4* ep = reinterpret_cast<const float4*>(&edge_attr[(long)eid * FE]);
#pragma unroll
      for (int k4 = 0; k4 < 4; k4++) {
        float4 u = ep[k4];
        eav[4 * k4 + 0] = u.x; eav[4 * k4 + 1] = u.y;
        eav[4 * k4 + 2] = u.z; eav[4 * k4 + 3] = u.w;
      }
    } else {
#pragma unroll
      for (int k = 0; k < FE; k++) eav[k] = ea_mean[k];
    }
    float xs[PC];
    ldbf<PC>(&xl[(long)s * HC + c0], xs);
    float part = 0.f;
#pragma unroll
    for (int j = 0; j < PC; j++) {
      int c = c0 + j;
      float ew = 0.f;
#pragma unroll
      for (int k = 0; k < FE; k++) ew += eav[k] * sWe[k * HC + c];
      float t = xs[j] + xd[j] + ew;
      float v = t > 0.f ? t : NS * t;
      part += v * sAtt[c];
    }
    part += __shfl_xor(part, 1);
    part += __shfl_xor(part, 2);
    part += __shfl_xor(part, 4);   // all 8 lanes of this head now hold the logit
    float mn = fmaxf(m, part);
    float scale = __expf(m - mn);  // first iter: m=-1e30 -> scale=0
    float a = __expf(part - mn);
    l = l * scale + a;
#pragma unroll
    for (int j = 0; j < PC; j++) acc[j] = acc[j] * scale + a * xs[j];
    m = mn;
  }
  float inv = 1.f / (l + 1e-16f);
  float v[PC];
#pragma unroll
  for (int j = 0; j < PC; j++) v[j] = acc[j] * inv + bo[c0 + j];
  stbf<PC>(&out[(long)i * HC + c0], v);
}

// ---------------- batchnorm ----------------
template <int HC>
__global__ void k_bn_stats(const u16* __restrict__ x, float* __restrict__ sum, float* __restrict__ sq) {
  long e0 = (long)blockIdx.x * 256 + threadIdx.x;
  long stride = (long)gridDim.x * 256;  // multiple of HC
  float s = 0.f, s2 = 0.f;
  for (long e = e0; e < (long)Nn * HC; e += stride) {
    float v = b2f(x[e]);
    s += v; s2 += v * v;
  }
  int ch = (int)(e0 % HC);
  atomicAdd(&sum[ch], s);
  atomicAdd(&sq[ch], s2);
}

template <int HC>
__global__ void k_bn_elu(u16* __restrict__ x, const float* __restrict__ sum, const float* __restrict__ sq,
                         const float* __restrict__ g, const float* __restrict__ bt) {
  long total = (long)Nn * HC;
  long stride = (long)gridDim.x * 256;
  for (long e = (long)blockIdx.x * 256 + threadIdx.x; e < total; e += stride) {
    int ch = (int)(e % HC);
    float mu = sum[ch] * (1.f / Nn);
    float var = sq[ch] * (1.f / Nn) - mu * mu;
    float rs = rsqrtf(var + EPS);
    float y = g[ch] * (b2f(x[e]) - mu) * rs + bt[ch];
    x[e] = f2b(y > 0.f ? y : __expf(y) - 1.f);
  }
}

// ---------------- layer 3 (1 head, 1 channel, concat=False) ----------------
__global__ __launch_bounds__(256) void k_gemv3(const u16* __restrict__ h2,
                                               const float* __restrict__ W3l, const float* __restrict__ b3l,
                                               const float* __restrict__ W3r, const float* __restrict__ b3r,
                                               float* __restrict__ xl3, float* __restrict__ xr3) {
  int lane = threadIdx.x & 63;
  int i = (blockIdx.x << 2) + (threadIdx.x >> 6);
  if (i >= Nn) return;
  float a = b2f(h2[(long)i * HC2 + lane]);
  float b = b2f(h2[(long)i * HC2 + 64 + lane]);
  float pl = a * W3l[lane] + b * W3l[64 + lane];
  float pr = a * W3r[lane] + b * W3r[64 + lane];
  for (int o = 1; o < 64; o <<= 1) { pl += __shfl_xor(pl, o); pr += __shfl_xor(pr, o); }
  if (lane == 0) { xl3[i] = pl + b3l[0]; xr3[i] = pr + b3r[0]; }
}

__global__ void k_final3(const int* __restrict__ rowptr, const int* __restrict__ srcp,
                         const int* __restrict__ eidp,
                         const float* __restrict__ xl3, const float* __restrict__ xr3,
                         const float* __restrict__ We3, const float* __restrict__ att3,
                         const float* __restrict__ edge_attr, const float* __restrict__ ea_mean,
                         const float* __restrict__ bo3, float* __restrict__ out) {
  int i = blockIdx.x * 256 + threadIdx.x;
  if (i >= Nn) return;
  float we[FE];
#pragma unroll
  for (int k = 0; k < FE; k++) we[k] = We3[k];
  float at = att3[0];
  float xd = xr3[i];
  float m = -1e30f, l = 0.f, o = 0.f;
  int p0 = rowptr[i], p1 = rowptr[i + 1];
  for (int p = p0; p < p1; p++) {
    int s = srcp[p], eid = eidp[p];
    if ((unsigned)s >= (unsigned)Nn) s = 0;       // safety clamp
    float ew = 0.f;
    if ((unsigned)eid < (unsigned)Ee) {
#pragma unroll
      for (int k = 0; k < FE; k++) ew += edge_attr[(long)eid * FE + k] * we[k];
    } else {
#pragma unroll
      for (int k = 0; k < FE; k++) ew += ea_mean[k] * we[k];
    }
    float xsv = xl3[s];
    float t = xsv + xd + ew;
    float v = t > 0.f ? t : NS * t;
    float logit = v * at;
    float mn = fmaxf(m, logit);
    float scale = __expf(m - mn);
    float a = __expf(logit - mn);
    l = l * scale + a;
    o = o * scale + a * xsv;
    m = mn;
  }
  out[i] = o / (l + 1e-16f) + bo3[0];
}

extern "C" void kernel_launch(void* const* d_in, const int* in_sizes, int n_in,
                              void* d_out, int out_size, void* d_ws, size_t ws_size,
                              hipStream_t stream) {
  const float* x    = (const float*)d_in[0];
  const int*   ei   = (const int*)d_in[1];
  const float* ea   = (const float*)d_in[2];
  const float* W1   = (const float*)d_in[3];
  const float* b1   = (const float*)d_in[4];
  const float* We1  = (const float*)d_in[5];
  const float* att1 = (const float*)d_in[6];
  const float* bo1  = (const float*)d_in[7];
  const float* g1   = (const float*)d_in[8];
  const float* bt1  = (const float*)d_in[9];
  const float* W2   = (const float*)d_in[10];
  const float* b2   = (const float*)d_in[11];
  const float* We2  = (const float*)d_in[12];
  const float* att2 = (const float*)d_in[13];
  const float* bo2  = (const float*)d_in[14];
  const float* g2   = (const float*)d_in[15];
  const float* bt2  = (const float*)d_in[16];
  const float* W3l  = (const float*)d_in[17];
  const float* b3l  = (const float*)d_in[18];
  const float* W3r  = (const float*)d_in[19];
  const float* b3r  = (const float*)d_in[20];
  const float* We3  = (const float*)d_in[21];
  const float* att3 = (const float*)d_in[22];
  const float* bo3  = (const float*)d_in[23];
  float* out = (float*)d_out;

  char* ws = (char*)d_ws;
  size_t off = 0;
  auto alloc = [&](size_t bytes) -> void* {
    void* p = ws + off;
    off = (off + bytes + 255) & ~(size_t)255;
    return p;
  };
  int*   deg     = (int*)alloc((size_t)Nn * 4);
  int*   rowptr  = (int*)alloc((size_t)(Nn + 1) * 4);
  int*   cursor  = (int*)alloc((size_t)Nn * 4);
  int*   srcp    = (int*)alloc((size_t)ET * 4);
  int*   eidp    = (int*)alloc((size_t)ET * 4);
  float* ea_mean = (float*)alloc((size_t)FE * 4);
  float* bn_sum  = (float*)alloc(256 * 4);
  float* bn_sq   = (float*)alloc(256 * 4);
  float* xl3     = (float*)alloc((size_t)Nn * 4);
  float* xr3     = (float*)alloc((size_t)Nn * 4);
  u16*   xlA     = (u16*)alloc((size_t)Nn * 256 * 2);   // xl1 / xl2 (bf16 internal)
  u16*   hB      = (u16*)alloc((size_t)Nn * 256 * 2);   // h1 / h2 (bf16 internal)
  // total ≈ 57 MB

  hipMemsetAsync(deg, 0, (size_t)Nn * 4, stream);
  hipMemsetAsync(cursor, 0, (size_t)Nn * 4, stream);
  hipMemsetAsync(ea_mean, 0, (size_t)FE * 4, stream);

  k_ea_mean<<<128, 256, 0, stream>>>(ea, ea_mean);
  k_deg<<<(ET + 255) / 256, 256, 0, stream>>>(ei, deg);
  k_scan<<<1, 1024, 0, stream>>>(deg, rowptr);
  k_scatter<<<(ET + 255) / 256, 256, 0, stream>>>(ei, rowptr, cursor, srcp, eidp);

  // ---- layer 1 ----
  k_gemm<FIN, HC1, float><<<dim3(HC1 / 64, (Nn + 63) / 64), 256, 0, stream>>>(x, W1, b1, xlA, Nn);
  k_node_attn<HC1, C1><<<(Nn + 3) / 4, 256, 0, stream>>>(rowptr, srcp, eidp, xlA, We1, att1,
                                                         ea, ea_mean, bo1, hB);
  hipMemsetAsync(bn_sum, 0, 256 * 4, stream);
  hipMemsetAsync(bn_sq, 0, 256 * 4, stream);
  k_bn_stats<HC1><<<128, 256, 0, stream>>>(hB, bn_sum, bn_sq);
  k_bn_elu<HC1><<<2048, 256, 0, stream>>>(hB, bn_sum, bn_sq, g1, bt1);

  // ---- layer 2 ----
  k_gemm<HC1, HC2, u16><<<dim3(HC2 / 64, (Nn + 63) / 64), 256, 0, stream>>>(hB, W2, b2, xlA, Nn);
  k_node_attn<HC2, C2><<<(Nn + 3) / 4, 256, 0, stream>>>(rowptr, srcp, eidp, xlA, We2, att2,
                                                         ea, ea_mean, bo2, hB);
  hipMemsetAsync(bn_sum, 0, 256 * 4, stream);
  hipMemsetAsync(bn_sq, 0, 256 * 4, stream);
  k_bn_stats<HC2><<<128, 256, 0, stream>>>(hB, bn_sum, bn_sq);
  k_bn_elu<HC2><<<2048, 256, 0, stream>>>(hB, bn_sum, bn_sq, g2, bt2);

  // ---- layer 3 ----
  k_gemv3<<<(Nn + 3) / 4, 256, 0, stream>>>(hB, W3l, b3l, W3r, b3r, xl3, xr3);
  k_final3<<<(Nn + 255) / 256, 256, 0, stream>>>(rowptr, srcp, eidp, xl3, xr3, We3, att3,
                                                 ea, ea_mean, bo3, out);
}

// Round 5
// 1125.780 us; speedup vs baseline: 1.0006x; 1.0006x over previous
//
#include <hip/hip_runtime.h>

typedef unsigned short u16;   // raw bf16 bits (INTERNAL storage only)

constexpr int Nn  = 50000;
constexpr int Ee  = 500000;
constexpr int ET  = Nn + Ee;      // edges incl. self-loops
constexpr int FIN = 128;
constexpr int FE  = 16;
constexpr int Hh  = 8;
constexpr int C1  = 32, HC1 = 256;
constexpr int C2  = 16, HC2 = 128;
constexpr float NS  = 0.2f;
constexpr float EPS = 1e-5f;

__device__ __forceinline__ float b2f(u16 u) { return __uint_as_float(((unsigned)u) << 16); }
__device__ __forceinline__ u16 f2b(float f) {
  unsigned u = __float_as_uint(f);
  u += 0x7FFF + ((u >> 16) & 1);          // round-to-nearest-even
  return (u16)(u >> 16);
}

template <int PC>
__device__ __forceinline__ void ldbf(const u16* p, float* o) {
  if constexpr (PC == 4) {
    ushort4 u = *reinterpret_cast<const ushort4*>(p);
    o[0] = b2f(u.x); o[1] = b2f(u.y); o[2] = b2f(u.z); o[3] = b2f(u.w);
  } else {
    ushort2 u = *reinterpret_cast<const ushort2*>(p);
    o[0] = b2f(u.x); o[1] = b2f(u.y);
  }
}
template <int PC>
__device__ __forceinline__ void stbf(u16* p, const float* v) {
  if constexpr (PC == 4) {
    ushort4 u; u.x = f2b(v[0]); u.y = f2b(v[1]); u.z = f2b(v[2]); u.w = f2b(v[3]);
    *reinterpret_cast<ushort4*>(p) = u;
  } else {
    ushort2 u; u.x = f2b(v[0]); u.y = f2b(v[1]);
    *reinterpret_cast<ushort2*>(p) = u;
  }
}

// 4-wide loaders for the GEMM A operand (fp32 input or bf16 internal)
__device__ __forceinline__ void ld4(const float* p, float* o) {
  float4 a = *reinterpret_cast<const float4*>(p);
  o[0] = a.x; o[1] = a.y; o[2] = a.z; o[3] = a.w;
}
__device__ __forceinline__ void ld4(const u16* p, float* o) {
  ushort4 a = *reinterpret_cast<const ushort4*>(p);
  o[0] = b2f(a.x); o[1] = b2f(a.y); o[2] = b2f(a.z); o[3] = b2f(a.w);
}

// ---------------- edge_attr mean (for self-loop fill) ----------------
__global__ void k_ea_mean(const float* __restrict__ ea, float* __restrict__ ea_mean) {
  __shared__ float s[256];
  int f  = threadIdx.x & 15;
  int r0 = (threadIdx.x >> 4) + blockIdx.x * 16;
  float acc = 0.f;
  for (int e = r0; e < Ee; e += gridDim.x * 16) acc += ea[e * FE + f];
  s[threadIdx.x] = acc;
  __syncthreads();
  if (threadIdx.x < 16) {
    float t = 0.f;
    for (int r = 0; r < 16; r++) t += s[r * 16 + threadIdx.x];
    atomicAdd(&ea_mean[threadIdx.x], t * (1.f / Ee));
  }
}

// ---------------- CSR build (by destination) ----------------
__global__ void k_deg(const int* __restrict__ ei, int* __restrict__ deg) {
  int e = blockIdx.x * 256 + threadIdx.x;
  if (e >= ET) return;
  int d = (e < Ee) ? ei[Ee + e] : (e - Ee);
  if ((unsigned)d >= (unsigned)Nn) d = 0;   // safety clamp
  atomicAdd(&deg[d], 1);
}

__global__ __launch_bounds__(1024) void k_scan(const int* __restrict__ deg, int* __restrict__ rowptr) {
  const int T = 1024;
  int t = threadIdx.x;
  const int CH = (Nn + T - 1) / T;  // 49
  int base = t * CH;
  int sum = 0;
  for (int i = 0; i < CH; i++) {
    int idx = base + i;
    if (idx < Nn) sum += deg[idx];
  }
  __shared__ int s[T];
  s[t] = sum;
  __syncthreads();
  for (int off = 1; off < T; off <<= 1) {
    int v = (t >= off) ? s[t - off] : 0;
    __syncthreads();
    s[t] += v;
    __syncthreads();
  }
  int run = (t == 0) ? 0 : s[t - 1];
  for (int i = 0; i < CH; i++) {
    int idx = base + i;
    if (idx < Nn) { rowptr[idx] = run; run += deg[idx]; }
  }
  if (t == T - 1) rowptr[Nn] = run;  // == ET
}

__global__ void k_scatter(const int* __restrict__ ei, const int* __restrict__ rowptr,
                          int* __restrict__ cursor, int* __restrict__ srcp,
                          int* __restrict__ eidp) {
  int e = blockIdx.x * 256 + threadIdx.x;
  if (e >= ET) return;
  int s, d;
  if (e < Ee) { s = ei[e]; d = ei[Ee + e]; } else { s = d = e - Ee; }
  if ((unsigned)s >= (unsigned)Nn) s = 0;   // safety clamp
  if ((unsigned)d >= (unsigned)Nn) d = 0;
  int pos = rowptr[d] + atomicAdd(&cursor[d], 1);
  srcp[pos] = s; eidp[pos] = e;
}

// ------- fp32 tiled GEMM: C[M,NN] = A[M,KK] @ W[KK,NN] + bias; C stored bf16 -------
template <int KK, int NN, typename AT>
__global__ __launch_bounds__(256) void k_gemm(const AT* __restrict__ A, const float* __restrict__ W,
                                              const float* __restrict__ bias, u16* __restrict__ C, int M) {
  __shared__ float As[16][68];
  __shared__ float Bs[16][68];
  int tid = threadIdx.x;
  int tx = tid & 15, ty = tid >> 4;
  int row0 = blockIdx.y * 64;
  int col0 = blockIdx.x * 64;
  float acc[4][4] = {};
  for (int kb = 0; kb < KK; kb += 16) {
    {  // A tile: 64 rows x 16 k, each thread 4 consecutive k
      int v = tid * 4;
      int kk = v & 15, rr = v >> 4;
      int r = row0 + rr;
      float a[4] = {0.f, 0.f, 0.f, 0.f};
      if (r < M) ld4(&A[(long)r * KK + kb + kk], a);
      As[kk + 0][rr] = a[0]; As[kk + 1][rr] = a[1];
      As[kk + 2][rr] = a[2]; As[kk + 3][rr] = a[3];
    }
    {  // W tile: 16 k x 64 cols
      int v = tid * 4;
      int cc = v & 63, kk = v >> 6;
      float4 w = *reinterpret_cast<const float4*>(&W[(long)(kb + kk) * NN + col0 + cc]);
      Bs[kk][cc + 0] = w.x; Bs[kk][cc + 1] = w.y;
      Bs[kk][cc + 2] = w.z; Bs[kk][cc + 3] = w.w;
    }
    __syncthreads();
#pragma unroll
    for (int kk = 0; kk < 16; kk++) {
      float a0 = As[kk][ty * 4 + 0], a1 = As[kk][ty * 4 + 1];
      float a2 = As[kk][ty * 4 + 2], a3 = As[kk][ty * 4 + 3];
      float b0 = Bs[kk][tx * 4 + 0], b1 = Bs[kk][tx * 4 + 1];
      float b2 = Bs[kk][tx * 4 + 2], b3 = Bs[kk][tx * 4 + 3];
      acc[0][0] += a0 * b0; acc[0][1] += a0 * b1; acc[0][2] += a0 * b2; acc[0][3] += a0 * b3;
      acc[1][0] += a1 * b0; acc[1][1] += a1 * b1; acc[1][2] += a1 * b2; acc[1][3] += a1 * b3;
      acc[2][0] += a2 * b0; acc[2][1] += a2 * b1; acc[2][2] += a2 * b2; acc[2][3] += a2 * b3;
      acc[3][0] += a3 * b0; acc[3][1] += a3 * b1; acc[3][2] += a3 * b2; acc[3][3] += a3 * b3;
    }
    __syncthreads();
  }
#pragma unroll
  for (int r = 0; r < 4; r++) {
    int rr = row0 + ty * 4 + r;
    if (rr >= M) continue;
    int cc0 = col0 + tx * 4;
    float v[4];
#pragma unroll
    for (int c = 0; c < 4; c++) v[c] = acc[r][c] + bias[cc0 + c];
    stbf<4>(&C[(long)rr * NN + cc0], v);
  }
}

// ---- fused GATv2 attention: logits + online softmax + aggregation ----
// WPN waves per node; each lane covers 2 consecutive channels (c0 = w*128 + lane*2).
// Head = C consecutive channels -> C/2 lanes per head, aligned groups; shfl_xor reduce.
// We fragment held in 32 REGISTERS per lane (no LDS traffic).
template <int HC, int C, int WPN>
__global__ __launch_bounds__(256) void k_node_attn(
    const int* __restrict__ rowptr, const int* __restrict__ srcp, const int* __restrict__ eidp,
    const u16* __restrict__ xl, const float* __restrict__ We, const float* __restrict__ att,
    const float* __restrict__ edge_attr, const float* __restrict__ ea_mean,
    const float* __restrict__ bo, u16* __restrict__ out) {
  int lane = threadIdx.x & 63;
  int gw = (blockIdx.x << 2) + (threadIdx.x >> 6);
  int i = gw / WPN;
  int w = gw % WPN;
  if (i >= Nn) return;
  int c0 = w * 128 + lane * 2;
  // We fragment in registers: wr0/wr1[k] = We[k][c0], We[k][c0+1]
  float wr0[FE], wr1[FE];
#pragma unroll
  for (int k = 0; k < FE; k++) {
    float2 t = *reinterpret_cast<const float2*>(&We[k * HC + c0]);
    wr0[k] = t.x; wr1[k] = t.y;
  }
  float at0 = att[c0], at1 = att[c0 + 1];
  float xd[2];
  ldbf<2>(&xl[(long)i * HC + c0], xd);
  // self-loop ew (constant): edge_attr mean through We
  float ews0 = 0.f, ews1 = 0.f;
#pragma unroll
  for (int k = 0; k < FE; k++) {
    float mk = ea_mean[k];
    ews0 += mk * wr0[k]; ews1 += mk * wr1[k];
  }
  float m = -1e30f, l = 0.f, acc0 = 0.f, acc1 = 0.f;
  int p0 = rowptr[i], p1 = rowptr[i + 1];
  for (int p = p0; p < p1; p++) {
    int s = srcp[p], eid = eidp[p];
    if ((unsigned)s >= (unsigned)Nn) s = 0;       // safety clamp
    float ew0, ew1;
    if (eid < Ee) {                                // wave-uniform branch
      const float4* ep = reinterpret_cast<const float4*>(&edge_attr[(long)eid * FE]);
      ew0 = 0.f; ew1 = 0.f;
#pragma unroll
      for (int k4 = 0; k4 < 4; k4++) {
        float4 u = ep[k4];
        ew0 += u.x * wr0[4 * k4 + 0] + u.y * wr0[4 * k4 + 1]
             + u.z * wr0[4 * k4 + 2] + u.w * wr0[4 * k4 + 3];
        ew1 += u.x * wr1[4 * k4 + 0] + u.y * wr1[4 * k4 + 1]
             + u.z * wr1[4 * k4 + 2] + u.w * wr1[4 * k4 + 3];
      }
    } else { ew0 = ews0; ew1 = ews1; }
    float xs[2];
    ldbf<2>(&xl[(long)s * HC + c0], xs);
    float t0 = xs[0] + xd[0] + ew0; t0 = t0 > 0.f ? t0 : NS * t0;
    float t1 = xs[1] + xd[1] + ew1; t1 = t1 > 0.f ? t1 : NS * t1;
    float part = t0 * at0 + t1 * at1;
    constexpr int RED = C / 2;                     // lanes per head
#pragma unroll
    for (int off = 1; off < RED; off <<= 1) part += __shfl_xor(part, off);
    float mn = fmaxf(m, part);
    float sc = __expf(m - mn);                     // first iter: m=-1e30 -> sc=0
    float a = __expf(part - mn);
    l = l * sc + a;
    acc0 = acc0 * sc + a * xs[0];
    acc1 = acc1 * sc + a * xs[1];
    m = mn;
  }
  float inv = 1.f / (l + 1e-16f);
  float v[2] = {acc0 * inv + bo[c0], acc1 * inv + bo[c0 + 1]};
  stbf<2>(&out[(long)i * HC + c0], v);
}

// ---------------- batchnorm ----------------
template <int HC>
__global__ void k_bn_stats(const u16* __restrict__ x, float* __restrict__ sum, float* __restrict__ sq) {
  long e0 = (long)blockIdx.x * 256 + threadIdx.x;
  long stride = (long)gridDim.x * 256;  // multiple of HC
  float s = 0.f, s2 = 0.f;
  for (long e = e0; e < (long)Nn * HC; e += stride) {
    float v = b2f(x[e]);
    s += v; s2 += v * v;
  }
  int ch = (int)(e0 % HC);
  atomicAdd(&sum[ch], s);
  atomicAdd(&sq[ch], s2);
}

template <int HC>
__global__ void k_bn_elu(u16* __restrict__ x, const float* __restrict__ sum, const float* __restrict__ sq,
                         const float* __restrict__ g, const float* __restrict__ bt) {
  long total = (long)Nn * HC;
  long stride = (long)gridDim.x * 256;
  for (long e = (long)blockIdx.x * 256 + threadIdx.x; e < total; e += stride) {
    int ch = (int)(e % HC);
    float mu = sum[ch] * (1.f / Nn);
    float var = sq[ch] * (1.f / Nn) - mu * mu;
    float rs = rsqrtf(var + EPS);
    float y = g[ch] * (b2f(x[e]) - mu) * rs + bt[ch];
    x[e] = f2b(y > 0.f ? y : __expf(y) - 1.f);
  }
}

// ---------------- layer 3 (1 head, 1 channel, concat=False) ----------------
__global__ __launch_bounds__(256) void k_gemv3(const u16* __restrict__ h2,
                                               const float* __restrict__ W3l, const float* __restrict__ b3l,
                                               const float* __restrict__ W3r, const float* __restrict__ b3r,
                                               float* __restrict__ xl3, float* __restrict__ xr3) {
  int lane = threadIdx.x & 63;
  int i = (blockIdx.x << 2) + (threadIdx.x >> 6);
  if (i >= Nn) return;
  float a = b2f(h2[(long)i * HC2 + lane]);
  float b = b2f(h2[(long)i * HC2 + 64 + lane]);
  float pl = a * W3l[lane] + b * W3l[64 + lane];
  float pr = a * W3r[lane] + b * W3r[64 + lane];
  for (int o = 1; o < 64; o <<= 1) { pl += __shfl_xor(pl, o); pr += __shfl_xor(pr, o); }
  if (lane == 0) { xl3[i] = pl + b3l[0]; xr3[i] = pr + b3r[0]; }
}

__global__ void k_final3(const int* __restrict__ rowptr, const int* __restrict__ srcp,
                         const int* __restrict__ eidp,
                         const float* __restrict__ xl3, const float* __restrict__ xr3,
                         const float* __restrict__ We3, const float* __restrict__ att3,
                         const float* __restrict__ edge_attr, const float* __restrict__ ea_mean,
                         const float* __restrict__ bo3, float* __restrict__ out) {
  int i = blockIdx.x * 256 + threadIdx.x;
  if (i >= Nn) return;
  float we[FE];
#pragma unroll
  for (int k = 0; k < FE; k++) we[k] = We3[k];
  float at = att3[0];
  float xd = xr3[i];
  float ews = 0.f;
#pragma unroll
  for (int k = 0; k < FE; k++) ews += ea_mean[k] * we[k];
  float m = -1e30f, l = 0.f, o = 0.f;
  int p0 = rowptr[i], p1 = rowptr[i + 1];
  for (int p = p0; p < p1; p++) {
    int s = srcp[p], eid = eidp[p];
    if ((unsigned)s >= (unsigned)Nn) s = 0;       // safety clamp
    float ew;
    if (eid < Ee) {
      ew = 0.f;
#pragma unroll
      for (int k = 0; k < FE; k++) ew += edge_attr[(long)eid * FE + k] * we[k];
    } else ew = ews;
    float xsv = xl3[s];
    float t = xsv + xd + ew;
    float v = t > 0.f ? t : NS * t;
    float logit = v * at;
    float mn = fmaxf(m, logit);
    float scale = __expf(m - mn);
    float a = __expf(logit - mn);
    l = l * scale + a;
    o = o * scale + a * xsv;
    m = mn;
  }
  out[i] = o / (l + 1e-16f) + bo3[0];
}

extern "C" void kernel_launch(void* const* d_in, const int* in_sizes, int n_in,
                              void* d_out, int out_size, void* d_ws, size_t ws_size,
                              hipStream_t stream) {
  const float* x    = (const float*)d_in[0];
  const int*   ei   = (const int*)d_in[1];
  const float* ea   = (const float*)d_in[2];
  const float* W1   = (const float*)d_in[3];
  const float* b1   = (const float*)d_in[4];
  const float* We1  = (const float*)d_in[5];
  const float* att1 = (const float*)d_in[6];
  const float* bo1  = (const float*)d_in[7];
  const float* g1   = (const float*)d_in[8];
  const float* bt1  = (const float*)d_in[9];
  const float* W2   = (const float*)d_in[10];
  const float* b2   = (const float*)d_in[11];
  const float* We2  = (const float*)d_in[12];
  const float* att2 = (const float*)d_in[13];
  const float* bo2  = (const float*)d_in[14];
  const float* g2   = (const float*)d_in[15];
  const float* bt2  = (const float*)d_in[16];
  const float* W3l  = (const float*)d_in[17];
  const float* b3l  = (const float*)d_in[18];
  const float* W3r  = (const float*)d_in[19];
  const float* b3r  = (const float*)d_in[20];
  const float* We3  = (const float*)d_in[21];
  const float* att3 = (const float*)d_in[22];
  const float* bo3  = (const float*)d_in[23];
  float* out = (float*)d_out;

  char* ws = (char*)d_ws;
  size_t off = 0;
  auto alloc = [&](size_t bytes) -> void* {
    void* p = ws + off;
    off = (off + bytes + 255) & ~(size_t)255;
    return p;
  };
  int*   deg     = (int*)alloc((size_t)Nn * 4);
  int*   rowptr  = (int*)alloc((size_t)(Nn + 1) * 4);
  int*   cursor  = (int*)alloc((size_t)Nn * 4);
  int*   srcp    = (int*)alloc((size_t)ET * 4);
  int*   eidp    = (int*)alloc((size_t)ET * 4);
  float* ea_mean = (float*)alloc((size_t)FE * 4);
  float* bn_sum  = (float*)alloc(256 * 4);
  float* bn_sq   = (float*)alloc(256 * 4);
  float* xl3     = (float*)alloc((size_t)Nn * 4);
  float* xr3     = (float*)alloc((size_t)Nn * 4);
  u16*   xlA     = (u16*)alloc((size_t)Nn * 256 * 2);   // xl1 / xl2 (bf16 internal)
  u16*   hB      = (u16*)alloc((size_t)Nn * 256 * 2);   // h1 / h2 (bf16 internal)
  // total ≈ 57 MB

  hipMemsetAsync(deg, 0, (size_t)Nn * 4, stream);
  hipMemsetAsync(cursor, 0, (size_t)Nn * 4, stream);
  hipMemsetAsync(ea_mean, 0, (size_t)FE * 4, stream);

  k_ea_mean<<<400, 256, 0, stream>>>(ea, ea_mean);
  k_deg<<<(ET + 255) / 256, 256, 0, stream>>>(ei, deg);
  k_scan<<<1, 1024, 0, stream>>>(deg, rowptr);
  k_scatter<<<(ET + 255) / 256, 256, 0, stream>>>(ei, rowptr, cursor, srcp, eidp);

  // ---- layer 1 ----
  k_gemm<FIN, HC1, float><<<dim3(HC1 / 64, (Nn + 63) / 64), 256, 0, stream>>>(x, W1, b1, xlA, Nn);
  k_node_attn<HC1, C1, 2><<<(Nn * 2 + 3) / 4, 256, 0, stream>>>(rowptr, srcp, eidp, xlA, We1, att1,
                                                                ea, ea_mean, bo1, hB);
  hipMemsetAsync(bn_sum, 0, 256 * 4, stream);
  hipMemsetAsync(bn_sq, 0, 256 * 4, stream);
  k_bn_stats<HC1><<<128, 256, 0, stream>>>(hB, bn_sum, bn_sq);
  k_bn_elu<HC1><<<2048, 256, 0, stream>>>(hB, bn_sum, bn_sq, g1, bt1);

  // ---- layer 2 ----
  k_gemm<HC1, HC2, u16><<<dim3(HC2 / 64, (Nn + 63) / 64), 256, 0, stream>>>(hB, W2, b2, xlA, Nn);
  k_node_attn<HC2, C2, 1><<<(Nn + 3) / 4, 256, 0, stream>>>(rowptr, srcp, eidp, xlA, We2, att2,
                                                            ea, ea_mean, bo2, hB);
  hipMemsetAsync(bn_sum, 0, 256 * 4, stream);
  hipMemsetAsync(bn_sq, 0, 256 * 4, stream);
  k_bn_stats<HC2><<<128, 256, 0, stream>>>(hB, bn_sum, bn_sq);
  k_bn_elu<HC2><<<2048, 256, 0, stream>>>(hB, bn_sum, bn_sq, g2, bt2);

  // ---- layer 3 ----
  k_gemv3<<<(Nn + 3) / 4, 256, 0, stream>>>(hB, W3l, b3l, W3r, b3r, xl3, xr3);
  k_final3<<<(Nn + 255) / 256, 256, 0, stream>>>(rowptr, srcp, eidp, xl3, xr3, We3, att3,
                                                 ea, ea_mean, bo3, out);
}

// Round 6
// 943.691 us; speedup vs baseline: 1.1936x; 1.1930x over previous
//
#include <hip/hip_runtime.h>

typedef unsigned short u16;   // raw bf16 bits (INTERNAL storage only)

constexpr int Nn  = 50000;
constexpr int Ee  = 500000;
constexpr int ET  = Nn + Ee;      // edges incl. self-loops
constexpr int FIN = 128;
constexpr int FE  = 16;
constexpr int Hh  = 8;
constexpr int C1  = 32, HC1 = 256;
constexpr int C2  = 16, HC2 = 128;
constexpr float NS  = 0.2f;
constexpr float EPS = 1e-5f;

__device__ __forceinline__ float b2f(u16 u) { return __uint_as_float(((unsigned)u) << 16); }
__device__ __forceinline__ u16 f2b(float f) {
  unsigned u = __float_as_uint(f);
  u += 0x7FFF + ((u >> 16) & 1);          // round-to-nearest-even
  return (u16)(u >> 16);
}

template <int PC>
__device__ __forceinline__ void ldbf(const u16* p, float* o) {
  if constexpr (PC == 4) {
    ushort4 u = *reinterpret_cast<const ushort4*>(p);
    o[0] = b2f(u.x); o[1] = b2f(u.y); o[2] = b2f(u.z); o[3] = b2f(u.w);
  } else {
    ushort2 u = *reinterpret_cast<const ushort2*>(p);
    o[0] = b2f(u.x); o[1] = b2f(u.y);
  }
}
template <int PC>
__device__ __forceinline__ void stbf(u16* p, const float* v) {
  if constexpr (PC == 4) {
    ushort4 u; u.x = f2b(v[0]); u.y = f2b(v[1]); u.z = f2b(v[2]); u.w = f2b(v[3]);
    *reinterpret_cast<ushort4*>(p) = u;
  } else {
    ushort2 u; u.x = f2b(v[0]); u.y = f2b(v[1]);
    *reinterpret_cast<ushort2*>(p) = u;
  }
}

// 4-wide loaders for the GEMM A operand (fp32 input or bf16 internal)
__device__ __forceinline__ void ld4(const float* p, float* o) {
  float4 a = *reinterpret_cast<const float4*>(p);
  o[0] = a.x; o[1] = a.y; o[2] = a.z; o[3] = a.w;
}
__device__ __forceinline__ void ld4(const u16* p, float* o) {
  ushort4 a = *reinterpret_cast<const ushort4*>(p);
  o[0] = b2f(a.x); o[1] = b2f(a.y); o[2] = b2f(a.z); o[3] = b2f(a.w);
}

// ---------------- edge_attr mean (for self-loop fill) ----------------
__global__ void k_ea_mean(const float* __restrict__ ea, float* __restrict__ ea_mean) {
  __shared__ float s[256];
  int f  = threadIdx.x & 15;
  int r0 = (threadIdx.x >> 4) + blockIdx.x * 16;
  float acc = 0.f;
  for (int e = r0; e < Ee; e += gridDim.x * 16) acc += ea[e * FE + f];
  s[threadIdx.x] = acc;
  __syncthreads();
  if (threadIdx.x < 16) {
    float t = 0.f;
    for (int r = 0; r < 16; r++) t += s[r * 16 + threadIdx.x];
    atomicAdd(&ea_mean[threadIdx.x], t * (1.f / Ee));
  }
}

// ---------------- CSR build (by destination) ----------------
__global__ void k_deg(const int* __restrict__ ei, int* __restrict__ deg) {
  int e = blockIdx.x * 256 + threadIdx.x;
  if (e >= ET) return;
  int d = (e < Ee) ? ei[Ee + e] : (e - Ee);
  if ((unsigned)d >= (unsigned)Nn) d = 0;   // safety clamp
  atomicAdd(&deg[d], 1);
}

__global__ __launch_bounds__(1024) void k_scan(const int* __restrict__ deg, int* __restrict__ rowptr) {
  const int T = 1024;
  int t = threadIdx.x;
  const int CH = (Nn + T - 1) / T;  // 49
  int base = t * CH;
  int sum = 0;
  for (int i = 0; i < CH; i++) {
    int idx = base + i;
    if (idx < Nn) sum += deg[idx];
  }
  __shared__ int s[T];
  s[t] = sum;
  __syncthreads();
  for (int off = 1; off < T; off <<= 1) {
    int v = (t >= off) ? s[t - off] : 0;
    __syncthreads();
    s[t] += v;
    __syncthreads();
  }
  int run = (t == 0) ? 0 : s[t - 1];
  for (int i = 0; i < CH; i++) {
    int idx = base + i;
    if (idx < Nn) { rowptr[idx] = run; run += deg[idx]; }
  }
  if (t == T - 1) rowptr[Nn] = run;  // == ET
}

__global__ void k_scatter(const int* __restrict__ ei, const int* __restrict__ rowptr,
                          int* __restrict__ cursor, int2* __restrict__ epack) {
  int e = blockIdx.x * 256 + threadIdx.x;
  if (e >= ET) return;
  int s, d;
  if (e < Ee) { s = ei[e]; d = ei[Ee + e]; } else { s = d = e - Ee; }
  if ((unsigned)s >= (unsigned)Nn) s = 0;   // safety clamp
  if ((unsigned)d >= (unsigned)Nn) d = 0;
  int pos = rowptr[d] + atomicAdd(&cursor[d], 1);
  epack[pos] = make_int2(s, e);
}

// ------- fp32 tiled GEMM: C[M,NN] = A[M,KK] @ W[KK,NN] + bias; C stored bf16 -------
template <int KK, int NN, typename AT>
__global__ __launch_bounds__(256) void k_gemm(const AT* __restrict__ A, const float* __restrict__ W,
                                              const float* __restrict__ bias, u16* __restrict__ C, int M) {
  __shared__ float As[16][68];
  __shared__ float Bs[16][68];
  int tid = threadIdx.x;
  int tx = tid & 15, ty = tid >> 4;
  int row0 = blockIdx.y * 64;
  int col0 = blockIdx.x * 64;
  float acc[4][4] = {};
  for (int kb = 0; kb < KK; kb += 16) {
    {  // A tile: 64 rows x 16 k, each thread 4 consecutive k
      int v = tid * 4;
      int kk = v & 15, rr = v >> 4;
      int r = row0 + rr;
      float a[4] = {0.f, 0.f, 0.f, 0.f};
      if (r < M) ld4(&A[(long)r * KK + kb + kk], a);
      As[kk + 0][rr] = a[0]; As[kk + 1][rr] = a[1];
      As[kk + 2][rr] = a[2]; As[kk + 3][rr] = a[3];
    }
    {  // W tile: 16 k x 64 cols
      int v = tid * 4;
      int cc = v & 63, kk = v >> 6;
      float4 w = *reinterpret_cast<const float4*>(&W[(long)(kb + kk) * NN + col0 + cc]);
      Bs[kk][cc + 0] = w.x; Bs[kk][cc + 1] = w.y;
      Bs[kk][cc + 2] = w.z; Bs[kk][cc + 3] = w.w;
    }
    __syncthreads();
#pragma unroll
    for (int kk = 0; kk < 16; kk++) {
      float a0 = As[kk][ty * 4 + 0], a1 = As[kk][ty * 4 + 1];
      float a2 = As[kk][ty * 4 + 2], a3 = As[kk][ty * 4 + 3];
      float b0 = Bs[kk][tx * 4 + 0], b1 = Bs[kk][tx * 4 + 1];
      float b2 = Bs[kk][tx * 4 + 2], b3 = Bs[kk][tx * 4 + 3];
      acc[0][0] += a0 * b0; acc[0][1] += a0 * b1; acc[0][2] += a0 * b2; acc[0][3] += a0 * b3;
      acc[1][0] += a1 * b0; acc[1][1] += a1 * b1; acc[1][2] += a1 * b2; acc[1][3] += a1 * b3;
      acc[2][0] += a2 * b0; acc[2][1] += a2 * b1; acc[2][2] += a2 * b2; acc[2][3] += a2 * b3;
      acc[3][0] += a3 * b0; acc[3][1] += a3 * b1; acc[3][2] += a3 * b2; acc[3][3] += a3 * b3;
    }
    __syncthreads();
  }
#pragma unroll
  for (int r = 0; r < 4; r++) {
    int rr = row0 + ty * 4 + r;
    if (rr >= M) continue;
    int cc0 = col0 + tx * 4;
    float v[4];
#pragma unroll
    for (int c = 0; c < 4; c++) v[c] = acc[r][c] + bias[cc0 + c];
    stbf<4>(&C[(long)rr * NN + cc0], v);
  }
}

// ---- fused GATv2 attention: logits + online softmax + aggregation ----
// WPN waves per node; each lane covers 2 consecutive channels (c0 = w*128 + lane*2).
// We fragment held in 32 registers; edge loop unrolled x4 with batched gathers (MLP).
template <int HC, int C, int WPN>
__global__ __launch_bounds__(256) void k_node_attn(
    const int* __restrict__ rowptr, const int2* __restrict__ epack,
    const u16* __restrict__ xl, const float* __restrict__ We, const float* __restrict__ att,
    const float* __restrict__ edge_attr, const float* __restrict__ ea_mean,
    const float* __restrict__ bo, u16* __restrict__ out) {
  int lane = threadIdx.x & 63;
  int gw = (blockIdx.x << 2) + (threadIdx.x >> 6);
  int i = gw / WPN;
  int w = gw % WPN;
  if (i >= Nn) return;
  int c0 = w * 128 + lane * 2;
  float wr0[FE], wr1[FE];
#pragma unroll
  for (int k = 0; k < FE; k++) {
    float2 t = *reinterpret_cast<const float2*>(&We[k * HC + c0]);
    wr0[k] = t.x; wr1[k] = t.y;
  }
  float at0 = att[c0], at1 = att[c0 + 1];
  float xd[2];
  ldbf<2>(&xl[(long)i * HC + c0], xd);
  float ews0 = 0.f, ews1 = 0.f;
#pragma unroll
  for (int k = 0; k < FE; k++) {
    float mk = ea_mean[k];
    ews0 += mk * wr0[k]; ews1 += mk * wr1[k];
  }
  float m = -1e30f, l = 0.f, acc0 = 0.f, acc1 = 0.f;
  int p0 = rowptr[i], p1 = rowptr[i + 1];
  constexpr int RED = C / 2;                       // lanes per head
  constexpr int UN = 4;
  int p = p0;
  for (; p + UN <= p1; p += UN) {
    int sA[UN], eA[UN];
#pragma unroll
    for (int j = 0; j < UN; j++) {                 // batched index loads
      int2 se = epack[p + j];
      int s = se.x;
      if ((unsigned)s >= (unsigned)Nn) s = 0;
      sA[j] = s; eA[j] = se.y;
    }
    float xs[UN][2];
#pragma unroll
    for (int j = 0; j < UN; j++)                   // issue all xl gathers
      ldbf<2>(&xl[(long)sA[j] * HC + c0], xs[j]);
    float ew0[UN], ew1[UN];
#pragma unroll
    for (int j = 0; j < UN; j++) {                 // issue all ea reads + dot
      int eid = eA[j];
      if (eid < Ee) {
        const float4* ep = reinterpret_cast<const float4*>(&edge_attr[(long)eid * FE]);
        float a0 = 0.f, a1 = 0.f;
#pragma unroll
        for (int k4 = 0; k4 < 4; k4++) {
          float4 u = ep[k4];
          a0 += u.x * wr0[4 * k4 + 0] + u.y * wr0[4 * k4 + 1]
              + u.z * wr0[4 * k4 + 2] + u.w * wr0[4 * k4 + 3];
          a1 += u.x * wr1[4 * k4 + 0] + u.y * wr1[4 * k4 + 1]
              + u.z * wr1[4 * k4 + 2] + u.w * wr1[4 * k4 + 3];
        }
        ew0[j] = a0; ew1[j] = a1;
      } else { ew0[j] = ews0; ew1[j] = ews1; }
    }
    float part[UN];
#pragma unroll
    for (int j = 0; j < UN; j++) {
      float t0 = xs[j][0] + xd[0] + ew0[j]; t0 = t0 > 0.f ? t0 : NS * t0;
      float t1 = xs[j][1] + xd[1] + ew1[j]; t1 = t1 > 0.f ? t1 : NS * t1;
      float pt = t0 * at0 + t1 * at1;
#pragma unroll
      for (int off = 1; off < RED; off <<= 1) pt += __shfl_xor(pt, off);
      part[j] = pt;
    }
    // batched online-softmax update (exact)
    float mn = m;
#pragma unroll
    for (int j = 0; j < UN; j++) mn = fmaxf(mn, part[j]);
    float sc = __expf(m - mn);
    float a[UN], asum = 0.f, ax0 = 0.f, ax1 = 0.f;
#pragma unroll
    for (int j = 0; j < UN; j++) {
      a[j] = __expf(part[j] - mn);
      asum += a[j]; ax0 += a[j] * xs[j][0]; ax1 += a[j] * xs[j][1];
    }
    l = l * sc + asum;
    acc0 = acc0 * sc + ax0;
    acc1 = acc1 * sc + ax1;
    m = mn;
  }
  for (; p < p1; p++) {                            // remainder
    int2 se = epack[p];
    int s = se.x, eid = se.y;
    if ((unsigned)s >= (unsigned)Nn) s = 0;
    float ew0, ew1;
    if (eid < Ee) {
      const float4* ep = reinterpret_cast<const float4*>(&edge_attr[(long)eid * FE]);
      ew0 = 0.f; ew1 = 0.f;
#pragma unroll
      for (int k4 = 0; k4 < 4; k4++) {
        float4 u = ep[k4];
        ew0 += u.x * wr0[4 * k4 + 0] + u.y * wr0[4 * k4 + 1]
             + u.z * wr0[4 * k4 + 2] + u.w * wr0[4 * k4 + 3];
        ew1 += u.x * wr1[4 * k4 + 0] + u.y * wr1[4 * k4 + 1]
             + u.z * wr1[4 * k4 + 2] + u.w * wr1[4 * k4 + 3];
      }
    } else { ew0 = ews0; ew1 = ews1; }
    float xs[2];
    ldbf<2>(&xl[(long)s * HC + c0], xs);
    float t0 = xs[0] + xd[0] + ew0; t0 = t0 > 0.f ? t0 : NS * t0;
    float t1 = xs[1] + xd[1] + ew1; t1 = t1 > 0.f ? t1 : NS * t1;
    float pt = t0 * at0 + t1 * at1;
#pragma unroll
    for (int off = 1; off < RED; off <<= 1) pt += __shfl_xor(pt, off);
    float mn = fmaxf(m, pt);
    float sc = __expf(m - mn);
    float a = __expf(pt - mn);
    l = l * sc + a;
    acc0 = acc0 * sc + a * xs[0];
    acc1 = acc1 * sc + a * xs[1];
    m = mn;
  }
  float inv = 1.f / (l + 1e-16f);
  float v[2] = {acc0 * inv + bo[c0], acc1 * inv + bo[c0 + 1]};
  stbf<2>(&out[(long)i * HC + c0], v);
}

// ---------------- batchnorm ----------------
template <int HC>
__global__ void k_bn_stats(const u16* __restrict__ x, float* __restrict__ sum, float* __restrict__ sq) {
  long e0 = (long)blockIdx.x * 256 + threadIdx.x;
  long stride = (long)gridDim.x * 256;  // multiple of HC
  float s = 0.f, s2 = 0.f;
  for (long e = e0; e < (long)Nn * HC; e += stride) {
    float v = b2f(x[e]);
    s += v; s2 += v * v;
  }
  int ch = (int)(e0 % HC);
  atomicAdd(&sum[ch], s);
  atomicAdd(&sq[ch], s2);
}

template <int HC>
__global__ void k_bn_elu(u16* __restrict__ x, const float* __restrict__ sum, const float* __restrict__ sq,
                         const float* __restrict__ g, const float* __restrict__ bt) {
  long total = (long)Nn * HC;
  long stride = (long)gridDim.x * 256;
  for (long e = (long)blockIdx.x * 256 + threadIdx.x; e < total; e += stride) {
    int ch = (int)(e % HC);
    float mu = sum[ch] * (1.f / Nn);
    float var = sq[ch] * (1.f / Nn) - mu * mu;
    float rs = rsqrtf(var + EPS);
    float y = g[ch] * (b2f(x[e]) - mu) * rs + bt[ch];
    x[e] = f2b(y > 0.f ? y : __expf(y) - 1.f);
  }
}

// ---------------- layer 3 (1 head, 1 channel, concat=False) ----------------
__global__ __launch_bounds__(256) void k_gemv3(const u16* __restrict__ h2,
                                               const float* __restrict__ W3l, const float* __restrict__ b3l,
                                               const float* __restrict__ W3r, const float* __restrict__ b3r,
                                               float* __restrict__ xl3, float* __restrict__ xr3) {
  int lane = threadIdx.x & 63;
  int i = (blockIdx.x << 2) + (threadIdx.x >> 6);
  if (i >= Nn) return;
  float a = b2f(h2[(long)i * HC2 + lane]);
  float b = b2f(h2[(long)i * HC2 + 64 + lane]);
  float pl = a * W3l[lane] + b * W3l[64 + lane];
  float pr = a * W3r[lane] + b * W3r[64 + lane];
  for (int o = 1; o < 64; o <<= 1) { pl += __shfl_xor(pl, o); pr += __shfl_xor(pr, o); }
  if (lane == 0) { xl3[i] = pl + b3l[0]; xr3[i] = pr + b3r[0]; }
}

__global__ void k_final3(const int* __restrict__ rowptr, const int2* __restrict__ epack,
                         const float* __restrict__ xl3, const float* __restrict__ xr3,
                         const float* __restrict__ We3, const float* __restrict__ att3,
                         const float* __restrict__ edge_attr, const float* __restrict__ ea_mean,
                         const float* __restrict__ bo3, float* __restrict__ out) {
  int i = blockIdx.x * 256 + threadIdx.x;
  if (i >= Nn) return;
  float we[FE];
#pragma unroll
  for (int k = 0; k < FE; k++) we[k] = We3[k];
  float at = att3[0];
  float xd = xr3[i];
  float ews = 0.f;
#pragma unroll
  for (int k = 0; k < FE; k++) ews += ea_mean[k] * we[k];
  float m = -1e30f, l = 0.f, o = 0.f;
  int p0 = rowptr[i], p1 = rowptr[i + 1];
  for (int p = p0; p < p1; p++) {
    int2 se = epack[p];
    int s = se.x, eid = se.y;
    if ((unsigned)s >= (unsigned)Nn) s = 0;       // safety clamp
    float ew;
    if (eid < Ee) {
      ew = 0.f;
#pragma unroll
      for (int k = 0; k < FE; k++) ew += edge_attr[(long)eid * FE + k] * we[k];
    } else ew = ews;
    float xsv = xl3[s];
    float t = xsv + xd + ew;
    float v = t > 0.f ? t : NS * t;
    float logit = v * at;
    float mn = fmaxf(m, logit);
    float scale = __expf(m - mn);
    float a = __expf(logit - mn);
    l = l * scale + a;
    o = o * scale + a * xsv;
    m = mn;
  }
  out[i] = o / (l + 1e-16f) + bo3[0];
}

extern "C" void kernel_launch(void* const* d_in, const int* in_sizes, int n_in,
                              void* d_out, int out_size, void* d_ws, size_t ws_size,
                              hipStream_t stream) {
  const float* x    = (const float*)d_in[0];
  const int*   ei   = (const int*)d_in[1];
  const float* ea   = (const float*)d_in[2];
  const float* W1   = (const float*)d_in[3];
  const float* b1   = (const float*)d_in[4];
  const float* We1  = (const float*)d_in[5];
  const float* att1 = (const float*)d_in[6];
  const float* bo1  = (const float*)d_in[7];
  const float* g1   = (const float*)d_in[8];
  const float* bt1  = (const float*)d_in[9];
  const float* W2   = (const float*)d_in[10];
  const float* b2   = (const float*)d_in[11];
  const float* We2  = (const float*)d_in[12];
  const float* att2 = (const float*)d_in[13];
  const float* bo2  = (const float*)d_in[14];
  const float* g2   = (const float*)d_in[15];
  const float* bt2  = (const float*)d_in[16];
  const float* W3l  = (const float*)d_in[17];
  const float* b3l  = (const float*)d_in[18];
  const float* W3r  = (const float*)d_in[19];
  const float* b3r  = (const float*)d_in[20];
  const float* We3  = (const float*)d_in[21];
  const float* att3 = (const float*)d_in[22];
  const float* bo3  = (const float*)d_in[23];
  float* out = (float*)d_out;

  char* ws = (char*)d_ws;
  size_t off = 0;
  auto alloc = [&](size_t bytes) -> void* {
    void* p = ws + off;
    off = (off + bytes + 255) & ~(size_t)255;
    return p;
  };
  int*   deg     = (int*)alloc((size_t)Nn * 4);
  int*   rowptr  = (int*)alloc((size_t)(Nn + 1) * 4);
  int*   cursor  = (int*)alloc((size_t)Nn * 4);
  int2*  epack   = (int2*)alloc((size_t)ET * 8);
  float* ea_mean = (float*)alloc((size_t)FE * 4);
  float* bn_sum  = (float*)alloc(256 * 4);
  float* bn_sq   = (float*)alloc(256 * 4);
  float* xl3     = (float*)alloc((size_t)Nn * 4);
  float* xr3     = (float*)alloc((size_t)Nn * 4);
  u16*   xlA     = (u16*)alloc((size_t)Nn * 256 * 2);   // xl1 / xl2 (bf16 internal)
  u16*   hB      = (u16*)alloc((size_t)Nn * 256 * 2);   // h1 / h2 (bf16 internal)
  // total ≈ 57 MB

  hipMemsetAsync(deg, 0, (size_t)Nn * 4, stream);
  hipMemsetAsync(cursor, 0, (size_t)Nn * 4, stream);
  hipMemsetAsync(ea_mean, 0, (size_t)FE * 4, stream);

  k_ea_mean<<<400, 256, 0, stream>>>(ea, ea_mean);
  k_deg<<<(ET + 255) / 256, 256, 0, stream>>>(ei, deg);
  k_scan<<<1, 1024, 0, stream>>>(deg, rowptr);
  k_scatter<<<(ET + 255) / 256, 256, 0, stream>>>(ei, rowptr, cursor, epack);

  // ---- layer 1 ----
  k_gemm<FIN, HC1, float><<<dim3(HC1 / 64, (Nn + 63) / 64), 256, 0, stream>>>(x, W1, b1, xlA, Nn);
  k_node_attn<HC1, C1, 2><<<(Nn * 2 + 3) / 4, 256, 0, stream>>>(rowptr, epack, xlA, We1, att1,
                                                                ea, ea_mean, bo1, hB);
  hipMemsetAsync(bn_sum, 0, 256 * 4, stream);
  hipMemsetAsync(bn_sq, 0, 256 * 4, stream);
  k_bn_stats<HC1><<<1024, 256, 0, stream>>>(hB, bn_sum, bn_sq);
  k_bn_elu<HC1><<<2048, 256, 0, stream>>>(hB, bn_sum, bn_sq, g1, bt1);

  // ---- layer 2 ----
  k_gemm<HC1, HC2, u16><<<dim3(HC2 / 64, (Nn + 63) / 64), 256, 0, stream>>>(hB, W2, b2, xlA, Nn);
  k_node_attn<HC2, C2, 1><<<(Nn + 3) / 4, 256, 0, stream>>>(rowptr, epack, xlA, We2, att2,
                                                            ea, ea_mean, bo2, hB);
  hipMemsetAsync(bn_sum, 0, 256 * 4, stream);
  hipMemsetAsync(bn_sq, 0, 256 * 4, stream);
  k_bn_stats<HC2><<<1024, 256, 0, stream>>>(hB, bn_sum, bn_sq);
  k_bn_elu<HC2><<<2048, 256, 0, stream>>>(hB, bn_sum, bn_sq, g2, bt2);

  // ---- layer 3 ----
  k_gemv3<<<(Nn + 3) / 4, 256, 0, stream>>>(hB, W3l, b3l, W3r, b3r, xl3, xr3);
  k_final3<<<(Nn + 255) / 256, 256, 0, stream>>>(rowptr, epack, xl3, xr3, We3, att3,
                                                 ea, ea_mean, bo3, out);
}

// Round 7
// 831.040 us; speedup vs baseline: 1.3554x; 1.1356x over previous
//
#include <hip/hip_runtime.h>

typedef unsigned short u16;   // raw bf16 bits (INTERNAL storage only)

constexpr int Nn  = 50000;
constexpr int Ee  = 500000;
constexpr int ET  = Nn + Ee;      // edges incl. self-loops
constexpr int FIN = 128;
constexpr int FE  = 16;
constexpr int Hh  = 8;
constexpr int C1  = 32, HC1 = 256;
constexpr int C2  = 16, HC2 = 128;
constexpr float NS  = 0.2f;
constexpr float EPS = 1e-5f;

__device__ __forceinline__ float b2f(u16 u) { return __uint_as_float(((unsigned)u) << 16); }
__device__ __forceinline__ u16 f2b(float f) {
  unsigned u = __float_as_uint(f);
  u += 0x7FFF + ((u >> 16) & 1);          // round-to-nearest-even
  return (u16)(u >> 16);
}

template <int PC>
__device__ __forceinline__ void ldbf(const u16* p, float* o) {
  if constexpr (PC == 4) {
    ushort4 u = *reinterpret_cast<const ushort4*>(p);
    o[0] = b2f(u.x); o[1] = b2f(u.y); o[2] = b2f(u.z); o[3] = b2f(u.w);
  } else {
    ushort2 u = *reinterpret_cast<const ushort2*>(p);
    o[0] = b2f(u.x); o[1] = b2f(u.y);
  }
}
template <int PC>
__device__ __forceinline__ void stbf(u16* p, const float* v) {
  if constexpr (PC == 4) {
    ushort4 u; u.x = f2b(v[0]); u.y = f2b(v[1]); u.z = f2b(v[2]); u.w = f2b(v[3]);
    *reinterpret_cast<ushort4*>(p) = u;
  } else {
    ushort2 u; u.x = f2b(v[0]); u.y = f2b(v[1]);
    *reinterpret_cast<ushort2*>(p) = u;
  }
}

// 4-wide loaders for the GEMM A operand (fp32 input or bf16 internal)
__device__ __forceinline__ void ld4(const float* p, float* o) {
  float4 a = *reinterpret_cast<const float4*>(p);
  o[0] = a.x; o[1] = a.y; o[2] = a.z; o[3] = a.w;
}
__device__ __forceinline__ void ld4(const u16* p, float* o) {
  ushort4 a = *reinterpret_cast<const ushort4*>(p);
  o[0] = b2f(a.x); o[1] = b2f(a.y); o[2] = b2f(a.z); o[3] = b2f(a.w);
}

// ---------------- edge_attr mean (for self-loop fill) ----------------
__global__ void k_ea_mean(const float* __restrict__ ea, float* __restrict__ ea_mean) {
  __shared__ float s[256];
  int f  = threadIdx.x & 15;
  int r0 = (threadIdx.x >> 4) + blockIdx.x * 16;
  float acc = 0.f;
  for (int e = r0; e < Ee; e += gridDim.x * 16) acc += ea[e * FE + f];
  s[threadIdx.x] = acc;
  __syncthreads();
  if (threadIdx.x < 16) {
    float t = 0.f;
    for (int r = 0; r < 16; r++) t += s[r * 16 + threadIdx.x];
    atomicAdd(&ea_mean[threadIdx.x], t * (1.f / Ee));
  }
}

// ---------------- CSR build (by destination) ----------------
__global__ void k_deg(const int* __restrict__ ei, int* __restrict__ deg) {
  int e = blockIdx.x * 256 + threadIdx.x;
  if (e >= ET) return;
  int d = (e < Ee) ? ei[Ee + e] : (e - Ee);
  if ((unsigned)d >= (unsigned)Nn) d = 0;   // safety clamp
  atomicAdd(&deg[d], 1);
}

__global__ __launch_bounds__(1024) void k_scan(const int* __restrict__ deg, int* __restrict__ rowptr) {
  const int T = 1024;
  int t = threadIdx.x;
  const int CH = (Nn + T - 1) / T;  // 49
  int base = t * CH;
  int sum = 0;
  for (int i = 0; i < CH; i++) {
    int idx = base + i;
    if (idx < Nn) sum += deg[idx];
  }
  __shared__ int s[T];
  s[t] = sum;
  __syncthreads();
  for (int off = 1; off < T; off <<= 1) {
    int v = (t >= off) ? s[t - off] : 0;
    __syncthreads();
    s[t] += v;
    __syncthreads();
  }
  int run = (t == 0) ? 0 : s[t - 1];
  for (int i = 0; i < CH; i++) {
    int idx = base + i;
    if (idx < Nn) { rowptr[idx] = run; run += deg[idx]; }
  }
  if (t == T - 1) rowptr[Nn] = run;  // == ET
}

__global__ void k_scatter(const int* __restrict__ ei, const int* __restrict__ rowptr,
                          int* __restrict__ cursor, int2* __restrict__ epack) {
  int e = blockIdx.x * 256 + threadIdx.x;
  if (e >= ET) return;
  int s, d;
  if (e < Ee) { s = ei[e]; d = ei[Ee + e]; } else { s = d = e - Ee; }
  if ((unsigned)s >= (unsigned)Nn) s = 0;   // safety clamp
  if ((unsigned)d >= (unsigned)Nn) d = 0;
  int pos = rowptr[d] + atomicAdd(&cursor[d], 1);
  epack[pos] = make_int2(s, e);
}

// ------- fp32 tiled GEMM: C[M,NN] = A[M,KK] @ W[KK,NN] + bias; C stored bf16 -------
template <int KK, int NN, typename AT>
__global__ __launch_bounds__(256) void k_gemm(const AT* __restrict__ A, const float* __restrict__ W,
                                              const float* __restrict__ bias, u16* __restrict__ C, int M) {
  __shared__ float As[16][68];
  __shared__ float Bs[16][68];
  int tid = threadIdx.x;
  int tx = tid & 15, ty = tid >> 4;
  int row0 = blockIdx.y * 64;
  int col0 = blockIdx.x * 64;
  float acc[4][4] = {};
  for (int kb = 0; kb < KK; kb += 16) {
    {  // A tile: 64 rows x 16 k, each thread 4 consecutive k
      int v = tid * 4;
      int kk = v & 15, rr = v >> 4;
      int r = row0 + rr;
      float a[4] = {0.f, 0.f, 0.f, 0.f};
      if (r < M) ld4(&A[(long)r * KK + kb + kk], a);
      As[kk + 0][rr] = a[0]; As[kk + 1][rr] = a[1];
      As[kk + 2][rr] = a[2]; As[kk + 3][rr] = a[3];
    }
    {  // W tile: 16 k x 64 cols
      int v = tid * 4;
      int cc = v & 63, kk = v >> 6;
      float4 w = *reinterpret_cast<const float4*>(&W[(long)(kb + kk) * NN + col0 + cc]);
      Bs[kk][cc + 0] = w.x; Bs[kk][cc + 1] = w.y;
      Bs[kk][cc + 2] = w.z; Bs[kk][cc + 3] = w.w;
    }
    __syncthreads();
#pragma unroll
    for (int kk = 0; kk < 16; kk++) {
      float a0 = As[kk][ty * 4 + 0], a1 = As[kk][ty * 4 + 1];
      float a2 = As[kk][ty * 4 + 2], a3 = As[kk][ty * 4 + 3];
      float b0 = Bs[kk][tx * 4 + 0], b1 = Bs[kk][tx * 4 + 1];
      float b2 = Bs[kk][tx * 4 + 2], b3 = Bs[kk][tx * 4 + 3];
      acc[0][0] += a0 * b0; acc[0][1] += a0 * b1; acc[0][2] += a0 * b2; acc[0][3] += a0 * b3;
      acc[1][0] += a1 * b0; acc[1][1] += a1 * b1; acc[1][2] += a1 * b2; acc[1][3] += a1 * b3;
      acc[2][0] += a2 * b0; acc[2][1] += a2 * b1; acc[2][2] += a2 * b2; acc[2][3] += a2 * b3;
      acc[3][0] += a3 * b0; acc[3][1] += a3 * b1; acc[3][2] += a3 * b2; acc[3][3] += a3 * b3;
    }
    __syncthreads();
  }
#pragma unroll
  for (int r = 0; r < 4; r++) {
    int rr = row0 + ty * 4 + r;
    if (rr >= M) continue;
    int cc0 = col0 + tx * 4;
    float v[4];
#pragma unroll
    for (int c = 0; c < 4; c++) v[c] = acc[r][c] + bias[cc0 + c];
    stbf<4>(&C[(long)rr * NN + cc0], v);
  }
}

// ---- fused GATv2 attention: logits + online softmax + aggregation ----
// Grid-stride over (node, w) with w fixed per wave: We/att/ea_mean setup hoisted.
// s/eid scalarized via readfirstlane -> saddr gathers + scalar edge_attr loads.
template <int HC, int C, int WPN>
__global__ __launch_bounds__(256) void k_node_attn(
    const int* __restrict__ rowptr, const int2* __restrict__ epack,
    const u16* __restrict__ xl, const float* __restrict__ We, const float* __restrict__ att,
    const float* __restrict__ edge_attr, const float* __restrict__ ea_mean,
    const float* __restrict__ bo, u16* __restrict__ out) {
  int lane = threadIdx.x & 63;
  int gwid = (blockIdx.x << 2) + (threadIdx.x >> 6);
  int nwaves = gridDim.x << 2;          // multiple of WPN by launch config
  int w = gwid % WPN;
  int i0 = gwid / WPN;
  int istride = nwaves / WPN;
  int c0 = w * 128 + lane * 2;
  // hoisted setup (loop-invariant)
  float wr0[FE], wr1[FE];
#pragma unroll
  for (int k = 0; k < FE; k++) {
    float2 t = *reinterpret_cast<const float2*>(&We[k * HC + c0]);
    wr0[k] = t.x; wr1[k] = t.y;
  }
  float at0 = att[c0], at1 = att[c0 + 1];
  float ews0 = 0.f, ews1 = 0.f;
#pragma unroll
  for (int k = 0; k < FE; k++) {
    float mk = ea_mean[k];
    ews0 += mk * wr0[k]; ews1 += mk * wr1[k];
  }
  float b0 = bo[c0], b1 = bo[c0 + 1];
  constexpr int RED = C / 2;                       // lanes per head
  constexpr int UN = 4;

  auto edge_ew = [&](int eid, float& e0, float& e1) {
    if (eid < Ee) {                                // scalar (uniform) branch
      const float4* ep = reinterpret_cast<const float4*>(&edge_attr[(size_t)eid * FE]);
      float a0 = 0.f, a1 = 0.f;
#pragma unroll
      for (int k4 = 0; k4 < 4; k4++) {
        float4 u = ep[k4];
        a0 += u.x * wr0[4 * k4 + 0] + u.y * wr0[4 * k4 + 1]
            + u.z * wr0[4 * k4 + 2] + u.w * wr0[4 * k4 + 3];
        a1 += u.x * wr1[4 * k4 + 0] + u.y * wr1[4 * k4 + 1]
            + u.z * wr1[4 * k4 + 2] + u.w * wr1[4 * k4 + 3];
      }
      e0 = a0; e1 = a1;
    } else { e0 = ews0; e1 = ews1; }
  };

  for (int i = i0; i < Nn; i += istride) {
    int p0 = rowptr[i], p1 = rowptr[i + 1];
    float xd[2];
    ldbf<2>(&xl[(size_t)i * HC + c0], xd);
    float m = -1e30f, l = 0.f, acc0 = 0.f, acc1 = 0.f;
    int p = p0;
    for (; p + UN <= p1; p += UN) {
      int sA[UN], eA[UN];
#pragma unroll
      for (int j = 0; j < UN; j++) {               // wave-uniform -> SGPRs
        int2 se = epack[p + j];
        sA[j] = __builtin_amdgcn_readfirstlane(se.x);
        eA[j] = __builtin_amdgcn_readfirstlane(se.y);
      }
      float xs[UN][2];
#pragma unroll
      for (int j = 0; j < UN; j++)                 // saddr-form coalesced loads
        ldbf<2>(&xl[(size_t)sA[j] * HC + c0], xs[j]);
      float ew0[UN], ew1[UN];
#pragma unroll
      for (int j = 0; j < UN; j++) edge_ew(eA[j], ew0[j], ew1[j]);
      float part[UN];
#pragma unroll
      for (int j = 0; j < UN; j++) {
        float t0 = xs[j][0] + xd[0] + ew0[j]; t0 = t0 > 0.f ? t0 : NS * t0;
        float t1 = xs[j][1] + xd[1] + ew1[j]; t1 = t1 > 0.f ? t1 : NS * t1;
        float pt = t0 * at0 + t1 * at1;
#pragma unroll
        for (int off = 1; off < RED; off <<= 1) pt += __shfl_xor(pt, off);
        part[j] = pt;
      }
      float mn = m;
#pragma unroll
      for (int j = 0; j < UN; j++) mn = fmaxf(mn, part[j]);
      float sc = __expf(m - mn);
      float a[UN], asum = 0.f, ax0 = 0.f, ax1 = 0.f;
#pragma unroll
      for (int j = 0; j < UN; j++) {
        a[j] = __expf(part[j] - mn);
        asum += a[j]; ax0 += a[j] * xs[j][0]; ax1 += a[j] * xs[j][1];
      }
      l = l * sc + asum;
      acc0 = acc0 * sc + ax0;
      acc1 = acc1 * sc + ax1;
      m = mn;
    }
    for (; p < p1; p++) {                          // remainder
      int2 se = epack[p];
      int s = __builtin_amdgcn_readfirstlane(se.x);
      int eid = __builtin_amdgcn_readfirstlane(se.y);
      float ew0, ew1;
      edge_ew(eid, ew0, ew1);
      float xs[2];
      ldbf<2>(&xl[(size_t)s * HC + c0], xs);
      float t0 = xs[0] + xd[0] + ew0; t0 = t0 > 0.f ? t0 : NS * t0;
      float t1 = xs[1] + xd[1] + ew1; t1 = t1 > 0.f ? t1 : NS * t1;
      float pt = t0 * at0 + t1 * at1;
#pragma unroll
      for (int off = 1; off < RED; off <<= 1) pt += __shfl_xor(pt, off);
      float mn = fmaxf(m, pt);
      float sc = __expf(m - mn);
      float a = __expf(pt - mn);
      l = l * sc + a;
      acc0 = acc0 * sc + a * xs[0];
      acc1 = acc1 * sc + a * xs[1];
      m = mn;
    }
    float inv = 1.f / (l + 1e-16f);
    float v[2] = {acc0 * inv + b0, acc1 * inv + b1};
    stbf<2>(&out[(size_t)i * HC + c0], v);
  }
}

// ---------------- batchnorm ----------------
template <int HC>
__global__ void k_bn_stats(const u16* __restrict__ x, float* __restrict__ sum, float* __restrict__ sq) {
  long e0 = (long)blockIdx.x * 256 + threadIdx.x;
  long stride = (long)gridDim.x * 256;  // multiple of HC
  float s = 0.f, s2 = 0.f;
  for (long e = e0; e < (long)Nn * HC; e += stride) {
    float v = b2f(x[e]);
    s += v; s2 += v * v;
  }
  int ch = (int)(e0 % HC);
  atomicAdd(&sum[ch], s);
  atomicAdd(&sq[ch], s2);
}

template <int HC>
__global__ void k_bn_elu(u16* __restrict__ x, const float* __restrict__ sum, const float* __restrict__ sq,
                         const float* __restrict__ g, const float* __restrict__ bt) {
  long total = (long)Nn * HC;
  long stride = (long)gridDim.x * 256;
  for (long e = (long)blockIdx.x * 256 + threadIdx.x; e < total; e += stride) {
    int ch = (int)(e % HC);
    float mu = sum[ch] * (1.f / Nn);
    float var = sq[ch] * (1.f / Nn) - mu * mu;
    float rs = rsqrtf(var + EPS);
    float y = g[ch] * (b2f(x[e]) - mu) * rs + bt[ch];
    x[e] = f2b(y > 0.f ? y : __expf(y) - 1.f);
  }
}

// ---------------- layer 3 (1 head, 1 channel, concat=False) ----------------
__global__ __launch_bounds__(256) void k_gemv3(const u16* __restrict__ h2,
                                               const float* __restrict__ W3l, const float* __restrict__ b3l,
                                               const float* __restrict__ W3r, const float* __restrict__ b3r,
                                               float* __restrict__ xl3, float* __restrict__ xr3) {
  int lane = threadIdx.x & 63;
  int i = (blockIdx.x << 2) + (threadIdx.x >> 6);
  if (i >= Nn) return;
  float a = b2f(h2[(long)i * HC2 + lane]);
  float b = b2f(h2[(long)i * HC2 + 64 + lane]);
  float pl = a * W3l[lane] + b * W3l[64 + lane];
  float pr = a * W3r[lane] + b * W3r[64 + lane];
  for (int o = 1; o < 64; o <<= 1) { pl += __shfl_xor(pl, o); pr += __shfl_xor(pr, o); }
  if (lane == 0) { xl3[i] = pl + b3l[0]; xr3[i] = pr + b3r[0]; }
}

// wave per node; lanes split edges; per-lane online softmax then cross-lane merge
__global__ __launch_bounds__(256) void k_final3(
    const int* __restrict__ rowptr, const int2* __restrict__ epack,
    const float* __restrict__ xl3, const float* __restrict__ xr3,
    const float* __restrict__ We3, const float* __restrict__ att3,
    const float* __restrict__ edge_attr, const float* __restrict__ ea_mean,
    const float* __restrict__ bo3, float* __restrict__ out) {
  int lane = threadIdx.x & 63;
  int i = (blockIdx.x << 2) + (threadIdx.x >> 6);
  if (i >= Nn) return;
  float we[FE];
#pragma unroll
  for (int k4 = 0; k4 < 4; k4++) {
    float4 u = reinterpret_cast<const float4*>(We3)[k4];
    we[4 * k4] = u.x; we[4 * k4 + 1] = u.y; we[4 * k4 + 2] = u.z; we[4 * k4 + 3] = u.w;
  }
  float at = att3[0];
  float ews = 0.f;
#pragma unroll
  for (int k = 0; k < FE; k++) ews += ea_mean[k] * we[k];
  float xd = xr3[i];
  int p0 = rowptr[i], p1 = rowptr[i + 1];
  float m = -1e30f, l = 0.f, o = 0.f;
  for (int p = p0 + lane; p < p1; p += 64) {
    int2 se = epack[p];
    int s = se.x, eid = se.y;
    float ew;
    if (eid < Ee) {
      const float4* ep = reinterpret_cast<const float4*>(&edge_attr[(size_t)eid * FE]);
      ew = 0.f;
#pragma unroll
      for (int k4 = 0; k4 < 4; k4++) {
        float4 u = ep[k4];
        ew += u.x * we[4 * k4] + u.y * we[4 * k4 + 1] + u.z * we[4 * k4 + 2] + u.w * we[4 * k4 + 3];
      }
    } else ew = ews;
    float xsv = xl3[s];
    float t = xsv + xd + ew;
    float v = t > 0.f ? t : NS * t;
    float logit = v * at;
    float mn = fmaxf(m, logit);
    float sc = __expf(m - mn);
    float a = __expf(logit - mn);
    l = l * sc + a;
    o = o * sc + a * xsv;
    m = mn;
  }
  // cross-lane merge
  float M = m;
#pragma unroll
  for (int off = 1; off < 64; off <<= 1) M = fmaxf(M, __shfl_xor(M, off));
  float adj = __expf(m - M);                       // lanes with no edges: 0
  float lw = l * adj, ow = o * adj;
#pragma unroll
  for (int off = 1; off < 64; off <<= 1) { lw += __shfl_xor(lw, off); ow += __shfl_xor(ow, off); }
  if (lane == 0) out[i] = ow / (lw + 1e-16f) + bo3[0];
}

extern "C" void kernel_launch(void* const* d_in, const int* in_sizes, int n_in,
                              void* d_out, int out_size, void* d_ws, size_t ws_size,
                              hipStream_t stream) {
  const float* x    = (const float*)d_in[0];
  const int*   ei   = (const int*)d_in[1];
  const float* ea   = (const float*)d_in[2];
  const float* W1   = (const float*)d_in[3];
  const float* b1   = (const float*)d_in[4];
  const float* We1  = (const float*)d_in[5];
  const float* att1 = (const float*)d_in[6];
  const float* bo1  = (const float*)d_in[7];
  const float* g1   = (const float*)d_in[8];
  const float* bt1  = (const float*)d_in[9];
  const float* W2   = (const float*)d_in[10];
  const float* b2   = (const float*)d_in[11];
  const float* We2  = (const float*)d_in[12];
  const float* att2 = (const float*)d_in[13];
  const float* bo2  = (const float*)d_in[14];
  const float* g2   = (const float*)d_in[15];
  const float* bt2  = (const float*)d_in[16];
  const float* W3l  = (const float*)d_in[17];
  const float* b3l  = (const float*)d_in[18];
  const float* W3r  = (const float*)d_in[19];
  const float* b3r  = (const float*)d_in[20];
  const float* We3  = (const float*)d_in[21];
  const float* att3 = (const float*)d_in[22];
  const float* bo3  = (const float*)d_in[23];
  float* out = (float*)d_out;

  char* ws = (char*)d_ws;
  size_t off = 0;
  auto alloc = [&](size_t bytes) -> void* {
    void* p = ws + off;
    off = (off + bytes + 255) & ~(size_t)255;
    return p;
  };
  int*   deg     = (int*)alloc((size_t)Nn * 4);
  int*   rowptr  = (int*)alloc((size_t)(Nn + 1) * 4);
  int*   cursor  = (int*)alloc((size_t)Nn * 4);
  int2*  epack   = (int2*)alloc((size_t)ET * 8);
  float* ea_mean = (float*)alloc((size_t)FE * 4);
  float* bn_sum  = (float*)alloc(256 * 4);
  float* bn_sq   = (float*)alloc(256 * 4);
  float* xl3     = (float*)alloc((size_t)Nn * 4);
  float* xr3     = (float*)alloc((size_t)Nn * 4);
  u16*   xlA     = (u16*)alloc((size_t)Nn * 256 * 2);   // xl1 / xl2 (bf16 internal)
  u16*   hB      = (u16*)alloc((size_t)Nn * 256 * 2);   // h1 / h2 (bf16 internal)
  // total ≈ 57 MB

  hipMemsetAsync(deg, 0, (size_t)Nn * 4, stream);
  hipMemsetAsync(cursor, 0, (size_t)Nn * 4, stream);
  hipMemsetAsync(ea_mean, 0, (size_t)FE * 4, stream);

  k_ea_mean<<<400, 256, 0, stream>>>(ea, ea_mean);
  k_deg<<<(ET + 255) / 256, 256, 0, stream>>>(ei, deg);
  k_scan<<<1, 1024, 0, stream>>>(deg, rowptr);
  k_scatter<<<(ET + 255) / 256, 256, 0, stream>>>(ei, rowptr, cursor, epack);

  // ---- layer 1 ----
  k_gemm<FIN, HC1, float><<<dim3(HC1 / 64, (Nn + 63) / 64), 256, 0, stream>>>(x, W1, b1, xlA, Nn);
  k_node_attn<HC1, C1, 2><<<2048, 256, 0, stream>>>(rowptr, epack, xlA, We1, att1,
                                                    ea, ea_mean, bo1, hB);
  hipMemsetAsync(bn_sum, 0, 256 * 4, stream);
  hipMemsetAsync(bn_sq, 0, 256 * 4, stream);
  k_bn_stats<HC1><<<256, 256, 0, stream>>>(hB, bn_sum, bn_sq);
  k_bn_elu<HC1><<<2048, 256, 0, stream>>>(hB, bn_sum, bn_sq, g1, bt1);

  // ---- layer 2 ----
  k_gemm<HC1, HC2, u16><<<dim3(HC2 / 64, (Nn + 63) / 64), 256, 0, stream>>>(hB, W2, b2, xlA, Nn);
  k_node_attn<HC2, C2, 1><<<2048, 256, 0, stream>>>(rowptr, epack, xlA, We2, att2,
                                                    ea, ea_mean, bo2, hB);
  hipMemsetAsync(bn_sum, 0, 256 * 4, stream);
  hipMemsetAsync(bn_sq, 0, 256 * 4, stream);
  k_bn_stats<HC2><<<256, 256, 0, stream>>>(hB, bn_sum, bn_sq);
  k_bn_elu<HC2><<<2048, 256, 0, stream>>>(hB, bn_sum, bn_sq, g2, bt2);

  // ---- layer 3 ----
  k_gemv3<<<(Nn + 3) / 4, 256, 0, stream>>>(hB, W3l, b3l, W3r, b3r, xl3, xr3);
  k_final3<<<(Nn + 3) / 4, 256, 0, stream>>>(rowptr, epack, xl3, xr3, We3, att3,
                                             ea, ea_mean, bo3, out);
}

// Round 8
// 781.103 us; speedup vs baseline: 1.4421x; 1.0639x over previous
//
#include <hip/hip_runtime.h>

typedef unsigned short u16;   // raw bf16 bits (INTERNAL storage only)
typedef __attribute__((ext_vector_type(4))) float f32x4;
typedef __attribute__((ext_vector_type(8))) short bf16x8;

constexpr int Nn  = 50000;
constexpr int Ee  = 500000;
constexpr int ET  = Nn + Ee;      // edges incl. self-loops
constexpr int FIN = 128;
constexpr int FE  = 16;
constexpr int Hh  = 8;
constexpr int C1  = 32, HC1 = 256;
constexpr int C2  = 16, HC2 = 128;
constexpr float NS  = 0.2f;
constexpr float EPS = 1e-5f;

__device__ __forceinline__ float b2f(u16 u) { return __uint_as_float(((unsigned)u) << 16); }
__device__ __forceinline__ u16 f2b(float f) {
  unsigned u = __float_as_uint(f);
  u += 0x7FFF + ((u >> 16) & 1);          // round-to-nearest-even
  return (u16)(u >> 16);
}

template <int PC>
__device__ __forceinline__ void ldbf(const u16* p, float* o) {
  if constexpr (PC == 4) {
    ushort4 u = *reinterpret_cast<const ushort4*>(p);
    o[0] = b2f(u.x); o[1] = b2f(u.y); o[2] = b2f(u.z); o[3] = b2f(u.w);
  } else {
    ushort2 u = *reinterpret_cast<const ushort2*>(p);
    o[0] = b2f(u.x); o[1] = b2f(u.y);
  }
}
template <int PC>
__device__ __forceinline__ void stbf(u16* p, const float* v) {
  if constexpr (PC == 4) {
    ushort4 u; u.x = f2b(v[0]); u.y = f2b(v[1]); u.z = f2b(v[2]); u.w = f2b(v[3]);
    *reinterpret_cast<ushort4*>(p) = u;
  } else {
    ushort2 u; u.x = f2b(v[0]); u.y = f2b(v[1]);
    *reinterpret_cast<ushort2*>(p) = u;
  }
}

// ---------------- edge_attr mean (for self-loop fill) ----------------
__global__ void k_ea_mean(const float* __restrict__ ea, float* __restrict__ ea_mean) {
  __shared__ float s[256];
  int f  = threadIdx.x & 15;
  int r0 = (threadIdx.x >> 4) + blockIdx.x * 16;
  float acc = 0.f;
  for (int e = r0; e < Ee; e += gridDim.x * 16) acc += ea[e * FE + f];
  s[threadIdx.x] = acc;
  __syncthreads();
  if (threadIdx.x < 16) {
    float t = 0.f;
    for (int r = 0; r < 16; r++) t += s[r * 16 + threadIdx.x];
    atomicAdd(&ea_mean[threadIdx.x], t * (1.f / Ee));
  }
}

// ---------------- CSR build (by destination) ----------------
__global__ void k_deg(const int* __restrict__ ei, int* __restrict__ deg) {
  int e = blockIdx.x * 256 + threadIdx.x;
  if (e >= ET) return;
  int d = (e < Ee) ? ei[Ee + e] : (e - Ee);
  if ((unsigned)d >= (unsigned)Nn) d = 0;   // safety clamp
  atomicAdd(&deg[d], 1);
}

__global__ __launch_bounds__(1024) void k_scan(const int* __restrict__ deg, int* __restrict__ rowptr) {
  const int T = 1024;
  int t = threadIdx.x;
  const int CH = (Nn + T - 1) / T;  // 49
  int base = t * CH;
  int sum = 0;
  for (int i = 0; i < CH; i++) {
    int idx = base + i;
    if (idx < Nn) sum += deg[idx];
  }
  __shared__ int s[T];
  s[t] = sum;
  __syncthreads();
  for (int off = 1; off < T; off <<= 1) {
    int v = (t >= off) ? s[t - off] : 0;
    __syncthreads();
    s[t] += v;
    __syncthreads();
  }
  int run = (t == 0) ? 0 : s[t - 1];
  for (int i = 0; i < CH; i++) {
    int idx = base + i;
    if (idx < Nn) { rowptr[idx] = run; run += deg[idx]; }
  }
  if (t == T - 1) rowptr[Nn] = run;  // == ET
}

__global__ void k_scatter(const int* __restrict__ ei, const int* __restrict__ rowptr,
                          int* __restrict__ cursor, int2* __restrict__ epack) {
  int e = blockIdx.x * 256 + threadIdx.x;
  if (e >= ET) return;
  int s, d;
  if (e < Ee) { s = ei[e]; d = ei[Ee + e]; } else { s = d = e - Ee; }
  if ((unsigned)s >= (unsigned)Nn) s = 0;   // safety clamp
  if ((unsigned)d >= (unsigned)Nn) d = 0;
  int pos = rowptr[d] + atomicAdd(&cursor[d], 1);
  epack[pos] = make_int2(s, e);
}

// ------- MFMA bf16 GEMM: C[M,NN] = A[M,KK] @ W[KK,NN] + bias; C stored bf16 -------
// Block: 4 waves, 64x64 tile. Wave w: rows [row0+w*16, +16), all 64 cols (4 n-tiles).
// W staged transposed in LDS as bf16, row stride KK+8 (2-way bank aliasing = free).
// Fragment layouts (gfx950, verified m89/m91): A[m=lane&15][k=quad*8+j],
// B[k=quad*8+j][n=lane&15], C/D[row=quad*4+reg][col=lane&15].
template <int KK, int NN, typename AT>
__global__ __launch_bounds__(256) void k_gemm_mfma(const AT* __restrict__ A, const float* __restrict__ W,
                                                   const float* __restrict__ bias, u16* __restrict__ C, int M) {
  constexpr int WT = KK + 8;
  __shared__ u16 Wt[64 * WT];
  int tid = threadIdx.x;
  int col0 = blockIdx.x * 64;
  int row0 = blockIdx.y * 64;
  for (int idx = tid; idx < KK * 64; idx += 256) {   // stage W -> LDS (transposed, bf16)
    int k = idx >> 6, c = idx & 63;
    Wt[c * WT + k] = f2b(W[(size_t)k * NN + col0 + c]);
  }
  __syncthreads();
  int lane = tid & 63;
  int w = tid >> 6;
  int mr = lane & 15, quad = lane >> 4;
  int row = row0 + w * 16 + mr;
  f32x4 acc[4];
#pragma unroll
  for (int t = 0; t < 4; t++) acc[t] = (f32x4){0.f, 0.f, 0.f, 0.f};
  union Frag { bf16x8 v; u16 u[8]; };
  for (int kb = 0; kb < KK; kb += 32) {
    Frag a;
    if (row < M) {
      if constexpr (sizeof(AT) == 4) {               // fp32 input -> convert
        const float* ap = (const float*)&A[(size_t)row * KK + kb + quad * 8];
        float4 a0 = *reinterpret_cast<const float4*>(ap);
        float4 a1 = *reinterpret_cast<const float4*>(ap + 4);
        a.u[0] = f2b(a0.x); a.u[1] = f2b(a0.y); a.u[2] = f2b(a0.z); a.u[3] = f2b(a0.w);
        a.u[4] = f2b(a1.x); a.u[5] = f2b(a1.y); a.u[6] = f2b(a1.z); a.u[7] = f2b(a1.w);
      } else {                                       // bf16 internal -> direct
        a.v = *reinterpret_cast<const bf16x8*>(&A[(size_t)row * KK + kb + quad * 8]);
      }
    } else {
#pragma unroll
      for (int j = 0; j < 8; j++) a.u[j] = 0;
    }
#pragma unroll
    for (int t = 0; t < 4; t++) {
      const bf16x8* bp = reinterpret_cast<const bf16x8*>(&Wt[(t * 16 + mr) * WT + kb + quad * 8]);
      acc[t] = __builtin_amdgcn_mfma_f32_16x16x32_bf16(a.v, *bp, acc[t], 0, 0, 0);
    }
  }
  int orow = row0 + w * 16 + quad * 4;
#pragma unroll
  for (int t = 0; t < 4; t++) {
    int col = col0 + t * 16 + mr;
    float bs = bias[col];
#pragma unroll
    for (int r = 0; r < 4; r++) {
      int rr = orow + r;
      if (rr < M) C[(size_t)rr * NN + col] = f2b(acc[t][r] + bs);
    }
  }
}

// ---- fused GATv2 attention: logits + online softmax + aggregation ----
// Grid-stride over (node, w) with w fixed per wave: We/att/ea_mean setup hoisted.
// s/eid scalarized via readfirstlane -> saddr gathers + scalar edge_attr loads.
template <int HC, int C, int WPN>
__global__ __launch_bounds__(256) void k_node_attn(
    const int* __restrict__ rowptr, const int2* __restrict__ epack,
    const u16* __restrict__ xl, const float* __restrict__ We, const float* __restrict__ att,
    const float* __restrict__ edge_attr, const float* __restrict__ ea_mean,
    const float* __restrict__ bo, u16* __restrict__ out) {
  int lane = threadIdx.x & 63;
  int gwid = (blockIdx.x << 2) + (threadIdx.x >> 6);
  int nwaves = gridDim.x << 2;          // multiple of WPN by launch config
  int w = gwid % WPN;
  int i0 = gwid / WPN;
  int istride = nwaves / WPN;
  int c0 = w * 128 + lane * 2;
  // hoisted setup (loop-invariant)
  float wr0[FE], wr1[FE];
#pragma unroll
  for (int k = 0; k < FE; k++) {
    float2 t = *reinterpret_cast<const float2*>(&We[k * HC + c0]);
    wr0[k] = t.x; wr1[k] = t.y;
  }
  float at0 = att[c0], at1 = att[c0 + 1];
  float ews0 = 0.f, ews1 = 0.f;
#pragma unroll
  for (int k = 0; k < FE; k++) {
    float mk = ea_mean[k];
    ews0 += mk * wr0[k]; ews1 += mk * wr1[k];
  }
  float b0 = bo[c0], b1 = bo[c0 + 1];
  constexpr int RED = C / 2;                       // lanes per head
  constexpr int UN = 4;

  auto edge_ew = [&](int eid, float& e0, float& e1) {
    if (eid < Ee) {                                // scalar (uniform) branch
      const float4* ep = reinterpret_cast<const float4*>(&edge_attr[(size_t)eid * FE]);
      float a0 = 0.f, a1 = 0.f;
#pragma unroll
      for (int k4 = 0; k4 < 4; k4++) {
        float4 u = ep[k4];
        a0 += u.x * wr0[4 * k4 + 0] + u.y * wr0[4 * k4 + 1]
            + u.z * wr0[4 * k4 + 2] + u.w * wr0[4 * k4 + 3];
        a1 += u.x * wr1[4 * k4 + 0] + u.y * wr1[4 * k4 + 1]
            + u.z * wr1[4 * k4 + 2] + u.w * wr1[4 * k4 + 3];
      }
      e0 = a0; e1 = a1;
    } else { e0 = ews0; e1 = ews1; }
  };

  for (int i = i0; i < Nn; i += istride) {
    int p0 = rowptr[i], p1 = rowptr[i + 1];
    float xd[2];
    ldbf<2>(&xl[(size_t)i * HC + c0], xd);
    float m = -1e30f, l = 0.f, acc0 = 0.f, acc1 = 0.f;
    int p = p0;
    for (; p + UN <= p1; p += UN) {
      int sA[UN], eA[UN];
#pragma unroll
      for (int j = 0; j < UN; j++) {               // wave-uniform -> SGPRs
        int2 se = epack[p + j];
        sA[j] = __builtin_amdgcn_readfirstlane(se.x);
        eA[j] = __builtin_amdgcn_readfirstlane(se.y);
      }
      float xs[UN][2];
#pragma unroll
      for (int j = 0; j < UN; j++)                 // saddr-form coalesced loads
        ldbf<2>(&xl[(size_t)sA[j] * HC + c0], xs[j]);
      float ew0[UN], ew1[UN];
#pragma unroll
      for (int j = 0; j < UN; j++) edge_ew(eA[j], ew0[j], ew1[j]);
      float part[UN];
#pragma unroll
      for (int j = 0; j < UN; j++) {
        float t0 = xs[j][0] + xd[0] + ew0[j]; t0 = t0 > 0.f ? t0 : NS * t0;
        float t1 = xs[j][1] + xd[1] + ew1[j]; t1 = t1 > 0.f ? t1 : NS * t1;
        float pt = t0 * at0 + t1 * at1;
#pragma unroll
        for (int off = 1; off < RED; off <<= 1) pt += __shfl_xor(pt, off);
        part[j] = pt;
      }
      float mn = m;
#pragma unroll
      for (int j = 0; j < UN; j++) mn = fmaxf(mn, part[j]);
      float sc = __expf(m - mn);
      float a[UN], asum = 0.f, ax0 = 0.f, ax1 = 0.f;
#pragma unroll
      for (int j = 0; j < UN; j++) {
        a[j] = __expf(part[j] - mn);
        asum += a[j]; ax0 += a[j] * xs[j][0]; ax1 += a[j] * xs[j][1];
      }
      l = l * sc + asum;
      acc0 = acc0 * sc + ax0;
      acc1 = acc1 * sc + ax1;
      m = mn;
    }
    for (; p < p1; p++) {                          // remainder
      int2 se = epack[p];
      int s = __builtin_amdgcn_readfirstlane(se.x);
      int eid = __builtin_amdgcn_readfirstlane(se.y);
      float ew0, ew1;
      edge_ew(eid, ew0, ew1);
      float xs[2];
      ldbf<2>(&xl[(size_t)s * HC + c0], xs);
      float t0 = xs[0] + xd[0] + ew0; t0 = t0 > 0.f ? t0 : NS * t0;
      float t1 = xs[1] + xd[1] + ew1; t1 = t1 > 0.f ? t1 : NS * t1;
      float pt = t0 * at0 + t1 * at1;
#pragma unroll
      for (int off = 1; off < RED; off <<= 1) pt += __shfl_xor(pt, off);
      float mn = fmaxf(m, pt);
      float sc = __expf(m - mn);
      float a = __expf(pt - mn);
      l = l * sc + a;
      acc0 = acc0 * sc + a * xs[0];
      acc1 = acc1 * sc + a * xs[1];
      m = mn;
    }
    float inv = 1.f / (l + 1e-16f);
    float v[2] = {acc0 * inv + b0, acc1 * inv + b1};
    stbf<2>(&out[(size_t)i * HC + c0], v);
  }
}

// ---------------- batchnorm ----------------
template <int HC>
__global__ void k_bn_stats(const u16* __restrict__ x, float* __restrict__ sum, float* __restrict__ sq) {
  long e0 = (long)blockIdx.x * 256 + threadIdx.x;
  long stride = (long)gridDim.x * 256;  // multiple of HC
  float s = 0.f, s2 = 0.f;
  for (long e = e0; e < (long)Nn * HC; e += stride) {
    float v = b2f(x[e]);
    s += v; s2 += v * v;
  }
  int ch = (int)(e0 % HC);
  atomicAdd(&sum[ch], s);
  atomicAdd(&sq[ch], s2);
}

template <int HC>
__global__ void k_bn_elu(u16* __restrict__ x, const float* __restrict__ sum, const float* __restrict__ sq,
                         const float* __restrict__ g, const float* __restrict__ bt) {
  long total = (long)Nn * HC;
  long stride = (long)gridDim.x * 256;
  for (long e = (long)blockIdx.x * 256 + threadIdx.x; e < total; e += stride) {
    int ch = (int)(e % HC);
    float mu = sum[ch] * (1.f / Nn);
    float var = sq[ch] * (1.f / Nn) - mu * mu;
    float rs = rsqrtf(var + EPS);
    float y = g[ch] * (b2f(x[e]) - mu) * rs + bt[ch];
    x[e] = f2b(y > 0.f ? y : __expf(y) - 1.f);
  }
}

// ---------------- layer 3 (1 head, 1 channel, concat=False) ----------------
__global__ __launch_bounds__(256) void k_gemv3(const u16* __restrict__ h2,
                                               const float* __restrict__ W3l, const float* __restrict__ b3l,
                                               const float* __restrict__ W3r, const float* __restrict__ b3r,
                                               float* __restrict__ xl3, float* __restrict__ xr3) {
  int lane = threadIdx.x & 63;
  int i = (blockIdx.x << 2) + (threadIdx.x >> 6);
  if (i >= Nn) return;
  float a = b2f(h2[(long)i * HC2 + lane]);
  float b = b2f(h2[(long)i * HC2 + 64 + lane]);
  float pl = a * W3l[lane] + b * W3l[64 + lane];
  float pr = a * W3r[lane] + b * W3r[64 + lane];
  for (int o = 1; o < 64; o <<= 1) { pl += __shfl_xor(pl, o); pr += __shfl_xor(pr, o); }
  if (lane == 0) { xl3[i] = pl + b3l[0]; xr3[i] = pr + b3r[0]; }
}

// wave per node; lanes split edges; per-lane online softmax then cross-lane merge
__global__ __launch_bounds__(256) void k_final3(
    const int* __restrict__ rowptr, const int2* __restrict__ epack,
    const float* __restrict__ xl3, const float* __restrict__ xr3,
    const float* __restrict__ We3, const float* __restrict__ att3,
    const float* __restrict__ edge_attr, const float* __restrict__ ea_mean,
    const float* __restrict__ bo3, float* __restrict__ out) {
  int lane = threadIdx.x & 63;
  int i = (blockIdx.x << 2) + (threadIdx.x >> 6);
  if (i >= Nn) return;
  float we[FE];
#pragma unroll
  for (int k4 = 0; k4 < 4; k4++) {
    float4 u = reinterpret_cast<const float4*>(We3)[k4];
    we[4 * k4] = u.x; we[4 * k4 + 1] = u.y; we[4 * k4 + 2] = u.z; we[4 * k4 + 3] = u.w;
  }
  float at = att3[0];
  float ews = 0.f;
#pragma unroll
  for (int k = 0; k < FE; k++) ews += ea_mean[k] * we[k];
  float xd = xr3[i];
  int p0 = rowptr[i], p1 = rowptr[i + 1];
  float m = -1e30f, l = 0.f, o = 0.f;
  for (int p = p0 + lane; p < p1; p += 64) {
    int2 se = epack[p];
    int s = se.x, eid = se.y;
    float ew;
    if (eid < Ee) {
      const float4* ep = reinterpret_cast<const float4*>(&edge_attr[(size_t)eid * FE]);
      ew = 0.f;
#pragma unroll
      for (int k4 = 0; k4 < 4; k4++) {
        float4 u = ep[k4];
        ew += u.x * we[4 * k4] + u.y * we[4 * k4 + 1] + u.z * we[4 * k4 + 2] + u.w * we[4 * k4 + 3];
      }
    } else ew = ews;
    float xsv = xl3[s];
    float t = xsv + xd + ew;
    float v = t > 0.f ? t : NS * t;
    float logit = v * at;
    float mn = fmaxf(m, logit);
    float sc = __expf(m - mn);
    float a = __expf(logit - mn);
    l = l * sc + a;
    o = o * sc + a * xsv;
    m = mn;
  }
  // cross-lane merge
  float M = m;
#pragma unroll
  for (int off = 1; off < 64; off <<= 1) M = fmaxf(M, __shfl_xor(M, off));
  float adj = __expf(m - M);                       // lanes with no edges: 0
  float lw = l * adj, ow = o * adj;
#pragma unroll
  for (int off = 1; off < 64; off <<= 1) { lw += __shfl_xor(lw, off); ow += __shfl_xor(ow, off); }
  if (lane == 0) out[i] = ow / (lw + 1e-16f) + bo3[0];
}

extern "C" void kernel_launch(void* const* d_in, const int* in_sizes, int n_in,
                              void* d_out, int out_size, void* d_ws, size_t ws_size,
                              hipStream_t stream) {
  const float* x    = (const float*)d_in[0];
  const int*   ei   = (const int*)d_in[1];
  const float* ea   = (const float*)d_in[2];
  const float* W1   = (const float*)d_in[3];
  const float* b1   = (const float*)d_in[4];
  const float* We1  = (const float*)d_in[5];
  const float* att1 = (const float*)d_in[6];
  const float* bo1  = (const float*)d_in[7];
  const float* g1   = (const float*)d_in[8];
  const float* bt1  = (const float*)d_in[9];
  const float* W2   = (const float*)d_in[10];
  const float* b2   = (const float*)d_in[11];
  const float* We2  = (const float*)d_in[12];
  const float* att2 = (const float*)d_in[13];
  const float* bo2  = (const float*)d_in[14];
  const float* g2   = (const float*)d_in[15];
  const float* bt2  = (const float*)d_in[16];
  const float* W3l  = (const float*)d_in[17];
  const float* b3l  = (const float*)d_in[18];
  const float* W3r  = (const float*)d_in[19];
  const float* b3r  = (const float*)d_in[20];
  const float* We3  = (const float*)d_in[21];
  const float* att3 = (const float*)d_in[22];
  const float* bo3  = (const float*)d_in[23];
  float* out = (float*)d_out;

  char* ws = (char*)d_ws;
  size_t off = 0;
  auto alloc = [&](size_t bytes) -> void* {
    void* p = ws + off;
    off = (off + bytes + 255) & ~(size_t)255;
    return p;
  };
  int*   deg     = (int*)alloc((size_t)Nn * 4);
  int*   rowptr  = (int*)alloc((size_t)(Nn + 1) * 4);
  int*   cursor  = (int*)alloc((size_t)Nn * 4);
  int2*  epack   = (int2*)alloc((size_t)ET * 8);
  float* ea_mean = (float*)alloc((size_t)FE * 4);
  float* bn_sum  = (float*)alloc(256 * 4);
  float* bn_sq   = (float*)alloc(256 * 4);
  float* xl3     = (float*)alloc((size_t)Nn * 4);
  float* xr3     = (float*)alloc((size_t)Nn * 4);
  u16*   xlA     = (u16*)alloc((size_t)Nn * 256 * 2);   // xl1 / xl2 (bf16 internal)
  u16*   hB      = (u16*)alloc((size_t)Nn * 256 * 2);   // h1 / h2 (bf16 internal)
  // total ≈ 57 MB

  hipMemsetAsync(deg, 0, (size_t)Nn * 4, stream);
  hipMemsetAsync(cursor, 0, (size_t)Nn * 4, stream);
  hipMemsetAsync(ea_mean, 0, (size_t)FE * 4, stream);

  k_ea_mean<<<400, 256, 0, stream>>>(ea, ea_mean);
  k_deg<<<(ET + 255) / 256, 256, 0, stream>>>(ei, deg);
  k_scan<<<1, 1024, 0, stream>>>(deg, rowptr);
  k_scatter<<<(ET + 255) / 256, 256, 0, stream>>>(ei, rowptr, cursor, epack);

  // ---- layer 1 ----
  k_gemm_mfma<FIN, HC1, float><<<dim3(HC1 / 64, (Nn + 63) / 64), 256, 0, stream>>>(x, W1, b1, xlA, Nn);
  k_node_attn<HC1, C1, 2><<<2048, 256, 0, stream>>>(rowptr, epack, xlA, We1, att1,
                                                    ea, ea_mean, bo1, hB);
  hipMemsetAsync(bn_sum, 0, 256 * 4, stream);
  hipMemsetAsync(bn_sq, 0, 256 * 4, stream);
  k_bn_stats<HC1><<<256, 256, 0, stream>>>(hB, bn_sum, bn_sq);
  k_bn_elu<HC1><<<2048, 256, 0, stream>>>(hB, bn_sum, bn_sq, g1, bt1);

  // ---- layer 2 ----
  k_gemm_mfma<HC1, HC2, u16><<<dim3(HC2 / 64, (Nn + 63) / 64), 256, 0, stream>>>(hB, W2, b2, xlA, Nn);
  k_node_attn<HC2, C2, 1><<<2048, 256, 0, stream>>>(rowptr, epack, xlA, We2, att2,
                                                    ea, ea_mean, bo2, hB);
  hipMemsetAsync(bn_sum, 0, 256 * 4, stream);
  hipMemsetAsync(bn_sq, 0, 256 * 4, stream);
  k_bn_stats<HC2><<<256, 256, 0, stream>>>(hB, bn_sum, bn_sq);
  k_bn_elu<HC2><<<2048, 256, 0, stream>>>(hB, bn_sum, bn_sq, g2, bt2);

  // ---- layer 3 ----
  k_gemv3<<<(Nn + 3) / 4, 256, 0, stream>>>(hB, W3l, b3l, W3r, b3r, xl3, xr3);
  k_final3<<<(Nn + 3) / 4, 256, 0, stream>>>(rowptr, epack, xl3, xr3, We3, att3,
                                             ea, ea_mean, bo3, out);
}

// Round 9
// 775.772 us; speedup vs baseline: 1.4520x; 1.0069x over previous
//
#include <hip/hip_runtime.h>

typedef unsigned short u16;   // raw bf16 bits (INTERNAL storage only)
typedef __attribute__((ext_vector_type(4))) float f32x4;
typedef __attribute__((ext_vector_type(2))) float f32x2;
typedef __attribute__((ext_vector_type(8))) short bf16x8;

constexpr int Nn  = 50000;
constexpr int Ee  = 500000;
constexpr int ET  = Nn + Ee;      // edges incl. self-loops
constexpr int FIN = 128;
constexpr int FE  = 16;
constexpr int Hh  = 8;
constexpr int C1  = 32, HC1 = 256;
constexpr int C2  = 16, HC2 = 128;
constexpr float NS  = 0.2f;
constexpr float EPS = 1e-5f;

__device__ __forceinline__ float b2f(u16 u) { return __uint_as_float(((unsigned)u) << 16); }
__device__ __forceinline__ u16 f2b(float f) {
  unsigned u = __float_as_uint(f);
  u += 0x7FFF + ((u >> 16) & 1);          // round-to-nearest-even
  return (u16)(u >> 16);
}
__device__ __forceinline__ f32x2 ldbf2(const u16* p) {
  ushort2 u = *reinterpret_cast<const ushort2*>(p);
  return (f32x2){b2f(u.x), b2f(u.y)};
}
__device__ __forceinline__ void stbf2(u16* p, f32x2 v) {
  ushort2 u; u.x = f2b(v.x); u.y = f2b(v.y);
  *reinterpret_cast<ushort2*>(p) = u;
}

// ---------------- edge_attr mean (for self-loop fill) ----------------
__global__ void k_ea_mean(const float* __restrict__ ea, float* __restrict__ ea_mean) {
  __shared__ float s[256];
  int f  = threadIdx.x & 15;
  int r0 = (threadIdx.x >> 4) + blockIdx.x * 16;
  float acc = 0.f;
  for (int e = r0; e < Ee; e += gridDim.x * 16) acc += ea[e * FE + f];
  s[threadIdx.x] = acc;
  __syncthreads();
  if (threadIdx.x < 16) {
    float t = 0.f;
    for (int r = 0; r < 16; r++) t += s[r * 16 + threadIdx.x];
    atomicAdd(&ea_mean[threadIdx.x], t * (1.f / Ee));
  }
}

// ---------------- CSR build (by destination) ----------------
__global__ void k_deg(const int* __restrict__ ei, int* __restrict__ deg) {
  int e = blockIdx.x * 256 + threadIdx.x;
  if (e >= ET) return;
  int d = (e < Ee) ? ei[Ee + e] : (e - Ee);
  if ((unsigned)d >= (unsigned)Nn) d = 0;   // safety clamp
  atomicAdd(&deg[d], 1);
}

__global__ __launch_bounds__(1024) void k_scan(const int* __restrict__ deg, int* __restrict__ rowptr) {
  const int T = 1024;
  int t = threadIdx.x;
  const int CH = (Nn + T - 1) / T;  // 49
  int base = t * CH;
  int sum = 0;
  for (int i = 0; i < CH; i++) {
    int idx = base + i;
    if (idx < Nn) sum += deg[idx];
  }
  __shared__ int s[T];
  s[t] = sum;
  __syncthreads();
  for (int off = 1; off < T; off <<= 1) {
    int v = (t >= off) ? s[t - off] : 0;
    __syncthreads();
    s[t] += v;
    __syncthreads();
  }
  int run = (t == 0) ? 0 : s[t - 1];
  for (int i = 0; i < CH; i++) {
    int idx = base + i;
    if (idx < Nn) { rowptr[idx] = run; run += deg[idx]; }
  }
  if (t == T - 1) rowptr[Nn] = run;  // == ET
}

__global__ void k_scatter(const int* __restrict__ ei, const int* __restrict__ rowptr,
                          int* __restrict__ cursor, int2* __restrict__ epack) {
  int e = blockIdx.x * 256 + threadIdx.x;
  if (e >= ET) return;
  int s, d;
  if (e < Ee) { s = ei[e]; d = ei[Ee + e]; } else { s = d = e - Ee; }
  if ((unsigned)s >= (unsigned)Nn) s = 0;   // safety clamp
  if ((unsigned)d >= (unsigned)Nn) d = 0;
  int pos = rowptr[d] + atomicAdd(&cursor[d], 1);
  epack[pos] = make_int2(s, e);
}

// ---------------- BN coefficients: scale/shift per channel ----------------
__global__ void k_bn_coef(const float* __restrict__ sum, const float* __restrict__ sq,
                          const float* __restrict__ g, const float* __restrict__ bt,
                          float2* __restrict__ coef, int HC) {
  int ch = threadIdx.x;
  if (ch >= HC) return;
  float mu = sum[ch] * (1.f / Nn);
  float var = sq[ch] * (1.f / Nn) - mu * mu;
  float rs = rsqrtf(var + EPS);
  float sc = g[ch] * rs;
  coef[ch] = make_float2(sc, bt[ch] - sc * mu);
}

// ------- MFMA bf16 GEMM: C[M,NN] = act(A)[M,KK] @ W[KK,NN] + bias; C stored bf16 -------
// FUSE: apply y = A*coef.x + coef.y, ELU elementwise to A before MFMA (BN+ELU fusion).
template <int KK, int NN, typename AT, bool FUSE>
__global__ __launch_bounds__(256) void k_gemm_mfma(const AT* __restrict__ A, const float* __restrict__ W,
                                                   const float* __restrict__ bias, u16* __restrict__ C,
                                                   const float2* __restrict__ coef, int M) {
  constexpr int WT = KK + 8;
  __shared__ u16 Wt[64 * WT];
  int tid = threadIdx.x;
  int col0 = blockIdx.x * 64;
  int row0 = blockIdx.y * 64;
  for (int idx = tid; idx < KK * 64; idx += 256) {   // stage W -> LDS (transposed, bf16)
    int k = idx >> 6, c = idx & 63;
    Wt[c * WT + k] = f2b(W[(size_t)k * NN + col0 + c]);
  }
  __syncthreads();
  int lane = tid & 63;
  int w = tid >> 6;
  int mr = lane & 15, quad = lane >> 4;
  int row = row0 + w * 16 + mr;
  f32x4 acc[4];
#pragma unroll
  for (int t = 0; t < 4; t++) acc[t] = (f32x4){0.f, 0.f, 0.f, 0.f};
  union Frag { bf16x8 v; u16 u[8]; };
  for (int kb = 0; kb < KK; kb += 32) {
    Frag a;
    if (row < M) {
      if constexpr (sizeof(AT) == 4) {               // fp32 input -> convert
        const float* ap = (const float*)&A[(size_t)row * KK + kb + quad * 8];
        float4 a0 = *reinterpret_cast<const float4*>(ap);
        float4 a1 = *reinterpret_cast<const float4*>(ap + 4);
        a.u[0] = f2b(a0.x); a.u[1] = f2b(a0.y); a.u[2] = f2b(a0.z); a.u[3] = f2b(a0.w);
        a.u[4] = f2b(a1.x); a.u[5] = f2b(a1.y); a.u[6] = f2b(a1.z); a.u[7] = f2b(a1.w);
      } else {                                       // bf16 internal
        a.v = *reinterpret_cast<const bf16x8*>(&A[(size_t)row * KK + kb + quad * 8]);
        if constexpr (FUSE) {
          int k0 = kb + quad * 8;
#pragma unroll
          for (int j = 0; j < 8; j++) {
            float2 c2 = coef[k0 + j];
            float y = b2f(a.u[j]) * c2.x + c2.y;
            y = y > 0.f ? y : __expf(y) - 1.f;       // ELU
            a.u[j] = f2b(y);
          }
        }
      }
    } else {
#pragma unroll
      for (int j = 0; j < 8; j++) a.u[j] = 0;
    }
#pragma unroll
    for (int t = 0; t < 4; t++) {
      const bf16x8* bp = reinterpret_cast<const bf16x8*>(&Wt[(t * 16 + mr) * WT + kb + quad * 8]);
      acc[t] = __builtin_amdgcn_mfma_f32_16x16x32_bf16(a.v, *bp, acc[t], 0, 0, 0);
    }
  }
  int orow = row0 + w * 16 + quad * 4;
#pragma unroll
  for (int t = 0; t < 4; t++) {
    int col = col0 + t * 16 + mr;
    float bs = bias[col];
#pragma unroll
    for (int r = 0; r < 4; r++) {
      int rr = orow + r;
      if (rr < M) C[(size_t)rr * NN + col] = f2b(acc[t][r] + bs);
    }
  }
}

// ---- fused GATv2 attention: logits + online softmax + aggregation ----
// Packed f32x2 math (v_pk_fma_f32); s/eid scalarized; grid-stride over (node, w).
template <int HC, int C, int WPN>
__global__ __launch_bounds__(256) void k_node_attn(
    const int* __restrict__ rowptr, const int2* __restrict__ epack,
    const u16* __restrict__ xl, const float* __restrict__ We, const float* __restrict__ att,
    const float* __restrict__ edge_attr, const float* __restrict__ ea_mean,
    const float* __restrict__ bo, u16* __restrict__ out) {
  int lane = threadIdx.x & 63;
  int gwid = (blockIdx.x << 2) + (threadIdx.x >> 6);
  int nwaves = gridDim.x << 2;          // multiple of WPN by launch config
  int w = gwid % WPN;
  int i0 = gwid / WPN;
  int istride = nwaves / WPN;
  int c0 = w * 128 + lane * 2;
  // hoisted setup: We column pair in registers (packed)
  f32x2 w2[FE];
#pragma unroll
  for (int k = 0; k < FE; k++) {
    float2 t = *reinterpret_cast<const float2*>(&We[k * HC + c0]);
    w2[k] = (f32x2){t.x, t.y};
  }
  float at0 = att[c0], at1 = att[c0 + 1];
  f32x2 ews2 = {0.f, 0.f};
#pragma unroll
  for (int k = 0; k < FE; k++) ews2 += ea_mean[k] * w2[k];
  float b0 = bo[c0], b1 = bo[c0 + 1];
  constexpr int RED = C / 2;                       // lanes per head
  constexpr int UN = 4;

  auto edge_ew = [&](int eid) -> f32x2 {
    if (eid < Ee) {                                // scalar (uniform) branch
      const float4* ep = reinterpret_cast<const float4*>(&edge_attr[(size_t)eid * FE]);
      f32x2 a = {0.f, 0.f};
#pragma unroll
      for (int k4 = 0; k4 < 4; k4++) {
        float4 u = ep[k4];
        a += u.x * w2[4 * k4 + 0];
        a += u.y * w2[4 * k4 + 1];
        a += u.z * w2[4 * k4 + 2];
        a += u.w * w2[4 * k4 + 3];
      }
      return a;
    }
    return ews2;
  };

  for (int i = i0; i < Nn; i += istride) {
    int p0 = rowptr[i], p1 = rowptr[i + 1];
    f32x2 xd = ldbf2(&xl[(size_t)i * HC + c0]);
    float m = -1e30f, l = 0.f;
    f32x2 acc = {0.f, 0.f};
    int p = p0;
    for (; p + UN <= p1; p += UN) {
      int sA[UN], eA[UN];
#pragma unroll
      for (int j = 0; j < UN; j++) {               // wave-uniform -> SGPRs
        int2 se = epack[p + j];
        sA[j] = __builtin_amdgcn_readfirstlane(se.x);
        eA[j] = __builtin_amdgcn_readfirstlane(se.y);
      }
      f32x2 xs[UN];
#pragma unroll
      for (int j = 0; j < UN; j++)                 // saddr-form coalesced loads
        xs[j] = ldbf2(&xl[(size_t)sA[j] * HC + c0]);
      f32x2 ew[UN];
#pragma unroll
      for (int j = 0; j < UN; j++) ew[j] = edge_ew(eA[j]);
      float part[UN];
#pragma unroll
      for (int j = 0; j < UN; j++) {
        f32x2 t = xs[j] + xd + ew[j];
        float t0 = t.x > 0.f ? t.x : NS * t.x;
        float t1 = t.y > 0.f ? t.y : NS * t.y;
        float pt = t0 * at0 + t1 * at1;
#pragma unroll
        for (int off = 1; off < RED; off <<= 1) pt += __shfl_xor(pt, off);
        part[j] = pt;
      }
      float mn = m;
#pragma unroll
      for (int j = 0; j < UN; j++) mn = fmaxf(mn, part[j]);
      float sc = __expf(m - mn);
      float a[UN], asum = 0.f;
      f32x2 ax = {0.f, 0.f};
#pragma unroll
      for (int j = 0; j < UN; j++) {
        a[j] = __expf(part[j] - mn);
        asum += a[j];
        ax += a[j] * xs[j];
      }
      l = l * sc + asum;
      acc = acc * sc + ax;
      m = mn;
    }
    for (; p < p1; p++) {                          // remainder
      int2 se = epack[p];
      int s = __builtin_amdgcn_readfirstlane(se.x);
      int eid = __builtin_amdgcn_readfirstlane(se.y);
      f32x2 ew = edge_ew(eid);
      f32x2 xs = ldbf2(&xl[(size_t)s * HC + c0]);
      f32x2 t = xs + xd + ew;
      float t0 = t.x > 0.f ? t.x : NS * t.x;
      float t1 = t.y > 0.f ? t.y : NS * t.y;
      float pt = t0 * at0 + t1 * at1;
#pragma unroll
      for (int off = 1; off < RED; off <<= 1) pt += __shfl_xor(pt, off);
      float mn = fmaxf(m, pt);
      float sc = __expf(m - mn);
      float a = __expf(pt - mn);
      l = l * sc + a;
      acc = acc * sc + a * xs;
      m = mn;
    }
    float inv = 1.f / (l + 1e-16f);
    f32x2 v = {acc.x * inv + b0, acc.y * inv + b1};
    stbf2(&out[(size_t)i * HC + c0], v);
  }
}

// ---------------- batchnorm stats ----------------
template <int HC>
__global__ void k_bn_stats(const u16* __restrict__ x, float* __restrict__ sum, float* __restrict__ sq) {
  long e0 = (long)blockIdx.x * 256 + threadIdx.x;
  long stride = (long)gridDim.x * 256;  // multiple of HC
  float s = 0.f, s2 = 0.f;
  for (long e = e0; e < (long)Nn * HC; e += stride) {
    float v = b2f(x[e]);
    s += v; s2 += v * v;
  }
  int ch = (int)(e0 % HC);
  atomicAdd(&sum[ch], s);
  atomicAdd(&sq[ch], s2);
}

// ------- layer 3 GEMV (with fused BN+ELU on h2) -------
__global__ __launch_bounds__(256) void k_gemv3(const u16* __restrict__ h2,
                                               const float2* __restrict__ coef,
                                               const float* __restrict__ W3l, const float* __restrict__ b3l,
                                               const float* __restrict__ W3r, const float* __restrict__ b3r,
                                               float* __restrict__ xl3, float* __restrict__ xr3) {
  int lane = threadIdx.x & 63;
  int i = (blockIdx.x << 2) + (threadIdx.x >> 6);
  if (i >= Nn) return;
  float2 ca = coef[lane], cb = coef[64 + lane];
  float a = b2f(h2[(long)i * HC2 + lane]) * ca.x + ca.y;
  a = a > 0.f ? a : __expf(a) - 1.f;
  float b = b2f(h2[(long)i * HC2 + 64 + lane]) * cb.x + cb.y;
  b = b > 0.f ? b : __expf(b) - 1.f;
  float pl = a * W3l[lane] + b * W3l[64 + lane];
  float pr = a * W3r[lane] + b * W3r[64 + lane];
  for (int o = 1; o < 64; o <<= 1) { pl += __shfl_xor(pl, o); pr += __shfl_xor(pr, o); }
  if (lane == 0) { xl3[i] = pl + b3l[0]; xr3[i] = pr + b3r[0]; }
}

// wave per node; lanes split edges; per-lane online softmax then cross-lane merge
__global__ __launch_bounds__(256) void k_final3(
    const int* __restrict__ rowptr, const int2* __restrict__ epack,
    const float* __restrict__ xl3, const float* __restrict__ xr3,
    const float* __restrict__ We3, const float* __restrict__ att3,
    const float* __restrict__ edge_attr, const float* __restrict__ ea_mean,
    const float* __restrict__ bo3, float* __restrict__ out) {
  int lane = threadIdx.x & 63;
  int i = (blockIdx.x << 2) + (threadIdx.x >> 6);
  if (i >= Nn) return;
  float we[FE];
#pragma unroll
  for (int k4 = 0; k4 < 4; k4++) {
    float4 u = reinterpret_cast<const float4*>(We3)[k4];
    we[4 * k4] = u.x; we[4 * k4 + 1] = u.y; we[4 * k4 + 2] = u.z; we[4 * k4 + 3] = u.w;
  }
  float at = att3[0];
  float ews = 0.f;
#pragma unroll
  for (int k = 0; k < FE; k++) ews += ea_mean[k] * we[k];
  float xd = xr3[i];
  int p0 = rowptr[i], p1 = rowptr[i + 1];
  float m = -1e30f, l = 0.f, o = 0.f;
  for (int p = p0 + lane; p < p1; p += 64) {
    int2 se = epack[p];
    int s = se.x, eid = se.y;
    float ew;
    if (eid < Ee) {
      const float4* ep = reinterpret_cast<const float4*>(&edge_attr[(size_t)eid * FE]);
      ew = 0.f;
#pragma unroll
      for (int k4 = 0; k4 < 4; k4++) {
        float4 u = ep[k4];
        ew += u.x * we[4 * k4] + u.y * we[4 * k4 + 1] + u.z * we[4 * k4 + 2] + u.w * we[4 * k4 + 3];
      }
    } else ew = ews;
    float xsv = xl3[s];
    float t = xsv + xd + ew;
    float v = t > 0.f ? t : NS * t;
    float logit = v * at;
    float mn = fmaxf(m, logit);
    float sc = __expf(m - mn);
    float a = __expf(logit - mn);
    l = l * sc + a;
    o = o * sc + a * xsv;
    m = mn;
  }
  // cross-lane merge
  float M = m;
#pragma unroll
  for (int off = 1; off < 64; off <<= 1) M = fmaxf(M, __shfl_xor(M, off));
  float adj = __expf(m - M);                       // lanes with no edges: 0
  float lw = l * adj, ow = o * adj;
#pragma unroll
  for (int off = 1; off < 64; off <<= 1) { lw += __shfl_xor(lw, off); ow += __shfl_xor(ow, off); }
  if (lane == 0) out[i] = ow / (lw + 1e-16f) + bo3[0];
}

extern "C" void kernel_launch(void* const* d_in, const int* in_sizes, int n_in,
                              void* d_out, int out_size, void* d_ws, size_t ws_size,
                              hipStream_t stream) {
  const float* x    = (const float*)d_in[0];
  const int*   ei   = (const int*)d_in[1];
  const float* ea   = (const float*)d_in[2];
  const float* W1   = (const float*)d_in[3];
  const float* b1   = (const float*)d_in[4];
  const float* We1  = (const float*)d_in[5];
  const float* att1 = (const float*)d_in[6];
  const float* bo1  = (const float*)d_in[7];
  const float* g1   = (const float*)d_in[8];
  const float* bt1  = (const float*)d_in[9];
  const float* W2   = (const float*)d_in[10];
  const float* b2   = (const float*)d_in[11];
  const float* We2  = (const float*)d_in[12];
  const float* att2 = (const float*)d_in[13];
  const float* bo2  = (const float*)d_in[14];
  const float* g2   = (const float*)d_in[15];
  const float* bt2  = (const float*)d_in[16];
  const float* W3l  = (const float*)d_in[17];
  const float* b3l  = (const float*)d_in[18];
  const float* W3r  = (const float*)d_in[19];
  const float* b3r  = (const float*)d_in[20];
  const float* We3  = (const float*)d_in[21];
  const float* att3 = (const float*)d_in[22];
  const float* bo3  = (const float*)d_in[23];
  float* out = (float*)d_out;

  char* ws = (char*)d_ws;
  size_t off = 0;
  auto alloc = [&](size_t bytes) -> void* {
    void* p = ws + off;
    off = (off + bytes + 255) & ~(size_t)255;
    return p;
  };
  int*    deg     = (int*)alloc((size_t)Nn * 4);
  int*    rowptr  = (int*)alloc((size_t)(Nn + 1) * 4);
  int*    cursor  = (int*)alloc((size_t)Nn * 4);
  int2*   epack   = (int2*)alloc((size_t)ET * 8);
  float*  ea_mean = (float*)alloc((size_t)FE * 4);
  float*  bn_sum  = (float*)alloc(256 * 4);
  float*  bn_sq   = (float*)alloc(256 * 4);
  float2* bncoef  = (float2*)alloc(256 * 8);
  float*  xl3     = (float*)alloc((size_t)Nn * 4);
  float*  xr3     = (float*)alloc((size_t)Nn * 4);
  u16*    xlA     = (u16*)alloc((size_t)Nn * 256 * 2);   // xl1 / xl2 (bf16 internal)
  u16*    hB      = (u16*)alloc((size_t)Nn * 256 * 2);   // h1 / h2 (bf16 internal, pre-BN)
  // total ≈ 57 MB

  hipMemsetAsync(deg, 0, (size_t)Nn * 4, stream);
  hipMemsetAsync(cursor, 0, (size_t)Nn * 4, stream);
  hipMemsetAsync(ea_mean, 0, (size_t)FE * 4, stream);

  k_ea_mean<<<400, 256, 0, stream>>>(ea, ea_mean);
  k_deg<<<(ET + 255) / 256, 256, 0, stream>>>(ei, deg);
  k_scan<<<1, 1024, 0, stream>>>(deg, rowptr);
  k_scatter<<<(ET + 255) / 256, 256, 0, stream>>>(ei, rowptr, cursor, epack);

  // ---- layer 1 ----
  k_gemm_mfma<FIN, HC1, float, false><<<dim3(HC1 / 64, (Nn + 63) / 64), 256, 0, stream>>>(
      x, W1, b1, xlA, nullptr, Nn);
  k_node_attn<HC1, C1, 2><<<2048, 256, 0, stream>>>(rowptr, epack, xlA, We1, att1,
                                                    ea, ea_mean, bo1, hB);
  hipMemsetAsync(bn_sum, 0, 256 * 4, stream);
  hipMemsetAsync(bn_sq, 0, 256 * 4, stream);
  k_bn_stats<HC1><<<256, 256, 0, stream>>>(hB, bn_sum, bn_sq);
  k_bn_coef<<<1, 256, 0, stream>>>(bn_sum, bn_sq, g1, bt1, bncoef, HC1);

  // ---- layer 2 (BN1+ELU fused into A-load) ----
  k_gemm_mfma<HC1, HC2, u16, true><<<dim3(HC2 / 64, (Nn + 63) / 64), 256, 0, stream>>>(
      hB, W2, b2, xlA, bncoef, Nn);
  k_node_attn<HC2, C2, 1><<<2048, 256, 0, stream>>>(rowptr, epack, xlA, We2, att2,
                                                    ea, ea_mean, bo2, hB);
  hipMemsetAsync(bn_sum, 0, 256 * 4, stream);
  hipMemsetAsync(bn_sq, 0, 256 * 4, stream);
  k_bn_stats<HC2><<<256, 256, 0, stream>>>(hB, bn_sum, bn_sq);
  k_bn_coef<<<1, 256, 0, stream>>>(bn_sum, bn_sq, g2, bt2, bncoef, HC2);

  // ---- layer 3 (BN2+ELU fused into h2 load) ----
  k_gemv3<<<(Nn + 3) / 4, 256, 0, stream>>>(hB, bncoef, W3l, b3l, W3r, b3r, xl3, xr3);
  k_final3<<<(Nn + 3) / 4, 256, 0, stream>>>(rowptr, epack, xl3, xr3, We3, att3,
                                             ea, ea_mean, bo3, out);
}